// Round 9
// baseline (325.937 us; speedup 1.0000x reference)
//
#include <hip/hip_runtime.h>
#include <math.h>

typedef _Float16 half8 __attribute__((ext_vector_type(8)));
typedef float floatx4 __attribute__((ext_vector_type(4)));
typedef float floatx2 __attribute__((ext_vector_type(2)));

#define B_ 8
#define S_ 4096
// scale = 1/sqrt(128) * log2(e): folded into Q so softmax exp is one v_exp_f32
#define SCALE_L2E 0.12751743008389106f
#define MASK_L2E  -14426.950408889634f   // -10000*log2(e): exp2 -> exact 0
#define L2_10K_OVER_128 0.10381025296522975f  // log2(10000)/128

#define PLD2 40   // P LDS row stride (halfs) = 80B, 16B-aligned; 32 cols + pad
#define KW  136   // prep K LDS row stride (halfs)
#define VW  24    // prep V^T LDS row stride (halfs)
#define OSTLD 136 // O-staging LDS row stride (halfs)
#define SLOTS_PER_B 576   // sum over qt32 of ceil(tiles/8)
#define NW 8      // waves per attn block
#define KVBUF 8192   // halfs per ring buffer: K 4096 | V 4096 (16KB)
#define NBUF 3       // 3-deep ring: single barrier per phase + depth-2 prefetch
#define POFF (NBUF * KVBUF)                       // 24576
#define POOL_HALFS (POFF + NW * 2 * 16 * PLD2)    // 34816 halfs = 69632 B

// units before q-block qt32 (chunks = floor(qt32/16)+1)
__device__ __forceinline__ int chunk_prefix(int qt32) {
    int g = qt32 >> 4;
    return qt32 + 8 * g * (g - 1) + (qt32 - (g << 4)) * g;
}

// async global->LDS, 16B per lane, wave-uniform LDS base (HW adds lane*16)
__device__ __forceinline__ void glds16(const _Float16* src, _Float16* dst) {
    __builtin_amdgcn_global_load_lds((const __attribute__((address_space(1))) void*)src,
                                     (__attribute__((address_space(3))) void*)dst, 16, 0, 0);
}

// ---------------- kernel 1: prep (R5 layouts; + counter zeroing) ----------------
// grid (256, 8), block 256: 16 seq rows per block.
//  Qh: RoPE(Q)*SCALE_L2E fp16 row-major [b][s][d]
//  Kp: frag-major: chunk(b,s16,c)[lane=quad*16+n][j] = K[s16*16+n][c*32+quad*8+j]
//  Vp: frag-major: chunk(b,kt,c2,nt)[lane=quad*16+n][j] = V[kt*64+c2*32+quad*8+j][nt*16+n]
__global__ __launch_bounds__(256) void prep_kernel(const float* __restrict__ qkv,
                                                   _Float16* __restrict__ Qh,
                                                   _Float16* __restrict__ Kp,
                                                   _Float16* __restrict__ Vp,
                                                   int* Cnt) {
    __shared__ __align__(16) _Float16 Kl[16][KW];
    __shared__ __align__(16) _Float16 Vt[128][VW];
    const int tid = threadIdx.x;
    const int b   = blockIdx.y;
    const int s0  = blockIdx.x * 16;

    // zero split-K completion counters (1024 ints) each launch
    if (Cnt && blockIdx.y == 0 && blockIdx.x < 4) Cnt[blockIdx.x * 256 + tid] = 0;

#pragma unroll
    for (int it = 0; it < 4; ++it) {
        int idx = tid + it * 256;
        int i = idx & 63, sr = idx >> 6, s = s0 + sr;
        const float* base = qkv + ((size_t)(b * S_ + s)) * 384 + 2 * i;
        floatx2 q2 = *(const floatx2*)base;
        floatx2 k2 = *(const floatx2*)(base + 128);
        float inv = exp2f(-(float)(2 * i) * L2_10K_OVER_128);
        float ang = (float)s * inv;
        float sn, cs;
        __sincosf(ang, &sn, &cs);
        size_t oq = ((size_t)(b * S_ + s)) * 128 + 2 * i;
        Qh[oq]     = (_Float16)((q2[0] * cs - q2[1] * sn) * SCALE_L2E);
        Qh[oq + 1] = (_Float16)((q2[0] * sn + q2[1] * cs) * SCALE_L2E);
        Kl[sr][2 * i]     = (_Float16)(k2[0] * cs - k2[1] * sn);
        Kl[sr][2 * i + 1] = (_Float16)(k2[0] * sn + k2[1] * cs);
    }
#pragma unroll
    for (int it = 0; it < 2; ++it) {
        int idx = tid + it * 256;
        int c = idx & 31, sr = idx >> 5;
        floatx4 v = *(const floatx4*)(qkv + ((size_t)(b * S_ + s0 + sr)) * 384 + 256 + c * 4);
#pragma unroll
        for (int j = 0; j < 4; ++j) Vt[c * 4 + j][sr] = (_Float16)v[j];
    }
    __syncthreads();

    {   // K frag-major out
        int c = tid >> 6, lane = tid & 63;
        int quad = lane >> 4, n = lane & 15;
        half8 val = *(const half8*)&Kl[n][c * 32 + quad * 8];
        int s16 = s0 >> 4;
        *(half8*)(Kp + (((size_t)(b * 256 + s16) * 4 + c) * 64 + lane) * 8) = val;
    }
    {   // V frag-major out
        int kt = s0 >> 6, c2 = (s0 >> 5) & 1, qp = (s0 >> 4) & 1;
        int nt = tid >> 5, lq = (tid >> 4) & 1, n = tid & 15;
        int quad = qp * 2 + lq;
        int lane = quad * 16 + n;
        half8 val = *(const half8*)&Vt[nt * 16 + n][lq * 8];
        *(half8*)(Vp + ((((size_t)(b * 64 + kt) * 2 + c2) * 8 + nt) * 64 + lane) * 8) = val;
    }
}

// ---------------- kernel 2: split-K flash + IN-KERNEL REDUCE FIXUP ----------------
// Inner loop = R5 exactly (best verified: 73.2us): grid (64,16) x=(b,chunk) so all
// blocks of batch b land on XCD b (L2 affinity for Kp/Vp AND Ppart); block 512 =
// 8 waves sharing (b,chunk); 3-buffer ring, 1 barrier/phase, depth-2 prefetch,
// counted vmcnt(2).
// R9: reduce_kernel is GONE. After storing partials, each wave fences + bumps a
// per-(b,qt32) counter; the last arriver sums the <=8 partials (L2-hot: same XCD
// wrote them), normalizes, writes f32 out. Saves one launch + the 36MB Ppart
// HBM round-trip that reduce_kernel paid.
__global__ __launch_bounds__(512) void attn_part_kernel(const _Float16* __restrict__ Qh,
                                                        const _Float16* __restrict__ Kp,
                                                        const _Float16* __restrict__ Vp,
                                                        _Float16* __restrict__ Ppart,
                                                        float* __restrict__ Lpart,
                                                        int* __restrict__ Cnt,
                                                        float* __restrict__ out) {
    __shared__ __align__(16) _Float16 POOL[POOL_HALFS];

    const int tid  = threadIdx.x;
    const int w    = tid >> 6;
    const int lane = tid & 63;
    const int quad = lane >> 4;
    const int l16  = lane & 15;
    const int b     = blockIdx.x & 7;
    const int chunk = blockIdx.x >> 3;
    const int c0    = chunk * 8;

    const int qt32_top  = 127 - blockIdx.y * 8;          // wave 0's qt32 (largest in block)
    const int ktmax_blk = (qt32_top * 32 + 31) >> 6;
    if (c0 > ktmax_blk) return;                          // uniform: whole block exits
    const int kend_blk  = min(ktmax_blk, c0 + 7);

    const int qt32   = qt32_top - w;
    const int qr0    = qt32 * 32;
    const int kt_max = (qr0 + 31) >> 6;
    const bool has_work = (c0 <= kt_max);
    const int kend   = min(kt_max, c0 + 7);
    const int slot   = b * SLOTS_PER_B + chunk_prefix(qt32) + chunk;
    _Float16* Pw = POOL + POFF + w * (2 * 16 * PLD2);

    half8 aq[2][4];
#pragma unroll
    for (int tile = 0; tile < 2; ++tile) {
        const _Float16* Qb = Qh + ((size_t)(b * S_) + qr0 + tile * 16 + l16) * 128;
#pragma unroll
        for (int c = 0; c < 4; ++c) aq[tile][c] = *(const half8*)(Qb + c * 32 + quad * 8);
    }

    floatx4 o[2][8];
#pragma unroll
    for (int tile = 0; tile < 2; ++tile)
#pragma unroll
        for (int i = 0; i < 8; ++i) o[tile][i] = (floatx4){0.f, 0.f, 0.f, 0.f};
    float rsum[2][4] = {{0.f, 0.f, 0.f, 0.f}, {0.f, 0.f, 0.f, 0.f}};

    const _Float16* Kb = Kp + (size_t)b * 524288;
    const _Float16* Vb = Vp + (size_t)b * 524288;

    const int ht0    = 2 * c0;            // half-tile index = kt*2 + h; K/V halfs at ht*4096
    const int ht_end = 2 * kend_blk + 1;  // >= ht0+1 always

    // stage half-tile ht_ into ring buffer ht_%3 (wave w moves 1KB K + 1KB V)
#define STAGE(ht_)                                                                \
    do {                                                                          \
        const _Float16* ks_ = Kb + (size_t)(ht_) * 4096 + w * 512 + lane * 8;     \
        const _Float16* vs_ = Vb + (size_t)(ht_) * 4096 + w * 512 + lane * 8;     \
        _Float16* d_ = POOL + ((ht_) % NBUF) * KVBUF + w * 512;                   \
        glds16(ks_, d_);                                                          \
        glds16(vs_, d_ + 4096);                                                   \
    } while (0)

    // prologue: stage the first two half-tiles (4 loads in flight)
    STAGE(ht0);
    STAGE(ht0 + 1);

    for (int ht = ht0; ht <= ht_end; ++ht) {
        if (ht < ht_end) {
            asm volatile("s_waitcnt vmcnt(2)" ::: "memory");  // buf[ht%3] loads retired
        } else {
            asm volatile("s_waitcnt vmcnt(0)" ::: "memory");
        }
        __builtin_amdgcn_s_barrier();
        if (ht + 2 <= ht_end) STAGE(ht + 2);

        const int kt = ht >> 1, h = ht & 1;
        if (has_work && kt <= kend) {
            const _Float16* Klds = POOL + (ht % NBUF) * KVBUF;
            const _Float16* Vlds = Klds + 4096;

            // S(:, local 32 cols) = Q K^T
            floatx4 s4[2][2];
#pragma unroll
            for (int tl = 0; tl < 2; ++tl) {
                half8 bk[4];
#pragma unroll
                for (int c = 0; c < 4; ++c)
                    bk[c] = *(const half8*)&Klds[((tl * 4 + c) * 64 + lane) * 8];
                floatx4 a0 = (floatx4){0.f, 0.f, 0.f, 0.f};
                floatx4 a1 = (floatx4){0.f, 0.f, 0.f, 0.f};
#pragma unroll
                for (int c = 0; c < 4; ++c) {
                    a0 = __builtin_amdgcn_mfma_f32_16x16x32_f16(aq[0][c], bk[c], a0, 0, 0, 0);
                    a1 = __builtin_amdgcn_mfma_f32_16x16x32_f16(aq[1][c], bk[c], a1, 0, 0, 0);
                }
                s4[0][tl] = a0; s4[1][tl] = a1;
            }

            // V frags: issue EARLY (no in-phase dependency) so ds_read latency
            // hides under the mask/exp/P-write VALU section below.
            half8 vf[8];
#pragma unroll
            for (int nt = 0; nt < 8; ++nt)
                vf[nt] = *(const half8*)&Vlds[(nt * 64 + lane) * 8];

            if (kt == kt_max) {  // causal mask, diagonal tile only
#pragma unroll
                for (int tile = 0; tile < 2; ++tile)
#pragma unroll
                    for (int tl = 0; tl < 2; ++tl)
#pragma unroll
                        for (int r = 0; r < 4; ++r) {
                            int kcol = kt * 64 + h * 32 + tl * 16 + l16;
                            int qr   = qr0 + tile * 16 + quad * 4 + r;
                            if (kcol > qr) s4[tile][tl][r] += MASK_L2E;
                        }
            }

            // p = exp2(s), lane-local l, P -> per-wave LDS (C->A layout transform)
#pragma unroll
            for (int tile = 0; tile < 2; ++tile)
#pragma unroll
                for (int tl = 0; tl < 2; ++tl)
#pragma unroll
                    for (int r = 0; r < 4; ++r) {
                        float p = __builtin_amdgcn_exp2f(s4[tile][tl][r]);
                        rsum[tile][r] += p;
                        Pw[tile * (16 * PLD2) + (quad * 4 + r) * PLD2 + tl * 16 + l16] = (_Float16)p;
                    }

            // O += P V  (this phase's 32 k-rows)
#pragma unroll
            for (int tile = 0; tile < 2; ++tile) {
                half8 ap = *(const half8*)&Pw[tile * (16 * PLD2) + l16 * PLD2 + quad * 8];
#pragma unroll
                for (int nt = 0; nt < 8; ++nt)
                    o[tile][nt] = __builtin_amdgcn_mfma_f32_16x16x32_f16(ap, vf[nt], o[tile][nt], 0, 0, 0);
            }
        }
    }
#undef STAGE

    // protect POOL reuse below: all waves done reading the ring
    __builtin_amdgcn_s_barrier();

    if (!has_work) return;

    // l partials: reduce over l16, plain store (no atomics)
#pragma unroll
    for (int off = 1; off <= 8; off <<= 1)
#pragma unroll
        for (int tile = 0; tile < 2; ++tile)
#pragma unroll
            for (int r = 0; r < 4; ++r)
                rsum[tile][r] += __shfl_xor(rsum[tile][r], off, 64);
    if (l16 == 0) {
#pragma unroll
        for (int tile = 0; tile < 2; ++tile)
#pragma unroll
            for (int r = 0; r < 4; ++r)
                Lpart[(size_t)slot * 32 + tile * 16 + quad * 4 + r] = rsum[tile][r];
    }

    // O partial: C-layout -> LDS fp16 staging (per-wave POOL slice) ->
    // coalesced 16B streaming stores. Per tile: 16 x OSTLD = 2176 halfs <= 4352.
    _Float16* Ost = POOL + w * (POOL_HALFS / NW);
    _Float16* pp = Ppart + (size_t)slot * 4096;
#pragma unroll
    for (int tile = 0; tile < 2; ++tile) {
#pragma unroll
        for (int nt = 0; nt < 8; ++nt)
#pragma unroll
            for (int r = 0; r < 4; ++r)
                Ost[(quad * 4 + r) * OSTLD + nt * 16 + l16] = (_Float16)o[tile][nt][r];
#pragma unroll
        for (int i = 0; i < 4; ++i) {
            int idx = lane + i * 64;        // half8-group: row=idx>>4, colgrp=idx&15
            half8 v = *(const half8*)&Ost[(idx >> 4) * OSTLD + (idx & 15) * 8];
            *(half8*)(pp + ((size_t)tile * 256 + idx) * 8) = v;
        }
    }

    // ---- split-K fixup: last-arriving wave of this (b, qt32) reduces + writes out.
    __threadfence();                       // publish Ppart/Lpart before counter bump
    int old = 0;
    if (lane == 0) old = atomicAdd(&Cnt[b * 128 + qt32], 1);
    old = __shfl(old, 0, 64);
    const int nch = (kt_max >> 3) + 1;     // chunks for this unit
    if (old == nch - 1) {
        __threadfence();                   // acquire: see other blocks' partials
        const size_t slot0 = (size_t)(b * SLOTS_PER_B + chunk_prefix(qt32));
        const _Float16* pr = Ppart + slot0 * 4096;
        const float*    lr = Lpart + slot0 * 32;
        float* ob = out + ((size_t)(b * S_) + qr0) * 128;
#pragma unroll
        for (int it = 0; it < 8; ++it) {
            int idx = lane + it * 64;      // half8-group 0..511
            int row = idx >> 4;
            float acc[8] = {0.f, 0.f, 0.f, 0.f, 0.f, 0.f, 0.f, 0.f};
            float l = 0.f;
            for (int c = 0; c < nch; ++c) {
                half8 v = *(const half8*)(pr + (size_t)c * 4096 + (size_t)idx * 8);
#pragma unroll
                for (int k = 0; k < 8; ++k) acc[k] += (float)v[k];
                l += lr[c * 32 + row];
            }
            float inv = 1.0f / l;
            float* op = ob + (size_t)idx * 8;
            *(floatx4*)op       = (floatx4){acc[0] * inv, acc[1] * inv, acc[2] * inv, acc[3] * inv};
            *(floatx4*)(op + 4) = (floatx4){acc[4] * inv, acc[5] * inv, acc[6] * inv, acc[7] * inv};
        }
    }
}

// ---------------- fallback (ws too small): R5 atomic path ----------------
#define PLD 72
__global__ __launch_bounds__(64) void attn_atomic_kernel(const _Float16* __restrict__ Qh,
                                                         const _Float16* __restrict__ Kp,
                                                         const _Float16* __restrict__ Vp,
                                                         float* __restrict__ out,
                                                         float* __restrict__ Lg) {
    __shared__ __align__(16) _Float16 Pl[2][16 * PLD];
    const int lane = threadIdx.x, quad = lane >> 4, l16 = lane & 15;
    const int b = blockIdx.x & 7, chunk = blockIdx.x >> 3;
    const int qt = 255 - blockIdx.y, qr0 = qt * 16;
    const int kt_max = qt >> 2, c0 = chunk * 8;
    if (c0 > kt_max) return;
    const int kend = min(kt_max, c0 + 7);
    const _Float16* Qb = Qh + ((size_t)(b * S_) + qr0 + l16) * 128;
    half8 aq[4];
#pragma unroll
    for (int c = 0; c < 4; ++c) aq[c] = *(const half8*)(Qb + c * 32 + quad * 8);
    floatx4 o[8];
#pragma unroll
    for (int i = 0; i < 8; ++i) o[i] = (floatx4){0.f, 0.f, 0.f, 0.f};
    float rsum[4] = {0.f, 0.f, 0.f, 0.f};
    const _Float16* Kb = Kp + (size_t)b * 524288;
    const _Float16* Vb = Vp + (size_t)b * 524288;
    for (int kt = c0; kt <= kend; ++kt) {
        half8 vf[2][8];
#pragma unroll
        for (int c2 = 0; c2 < 2; ++c2)
#pragma unroll
            for (int nt = 0; nt < 8; ++nt)
                vf[c2][nt] = *(const half8*)(Vb + (((size_t)(kt * 2 + c2) * 8 + nt) * 64 + lane) * 8);
        floatx4 s4[4];
#pragma unroll
        for (int t = 0; t < 4; ++t) {
            const _Float16* kp = Kb + ((size_t)((kt * 4 + t) * 4) * 64 + lane) * 8;
            floatx4 acc = (floatx4){0.f, 0.f, 0.f, 0.f};
#pragma unroll
            for (int c = 0; c < 4; ++c) {
                half8 bk = *(const half8*)(kp + c * 512);
                acc = __builtin_amdgcn_mfma_f32_16x16x32_f16(aq[c], bk, acc, 0, 0, 0);
            }
            s4[t] = acc;
        }
        if (kt == kt_max) {
#pragma unroll
            for (int t = 0; t < 4; ++t)
#pragma unroll
                for (int r = 0; r < 4; ++r) {
                    int kcol = kt * 64 + t * 16 + l16;
                    int qr = qr0 + quad * 4 + r;
                    if (kcol > qr) s4[t][r] += MASK_L2E;
                }
        }
        const int buf = kt & 1;
#pragma unroll
        for (int t = 0; t < 4; ++t)
#pragma unroll
            for (int r = 0; r < 4; ++r) {
                float p = __builtin_amdgcn_exp2f(s4[t][r]);
                rsum[r] += p;
                Pl[buf][(quad * 4 + r) * PLD + t * 16 + l16] = (_Float16)p;
            }
#pragma unroll
        for (int c2 = 0; c2 < 2; ++c2) {
            half8 ap = *(const half8*)&Pl[buf][l16 * PLD + c2 * 32 + quad * 8];
#pragma unroll
            for (int nt = 0; nt < 8; ++nt)
                o[nt] = __builtin_amdgcn_mfma_f32_16x16x32_f16(ap, vf[c2][nt], o[nt], 0, 0, 0);
        }
    }
#pragma unroll
    for (int off = 1; off <= 8; off <<= 1)
#pragma unroll
        for (int r = 0; r < 4; ++r)
            rsum[r] += __shfl_xor(rsum[r], off, 64);
    if (l16 == 0) {
#pragma unroll
        for (int r = 0; r < 4; ++r)
            atomicAdd(&Lg[(size_t)(b * S_) + qr0 + quad * 4 + r], rsum[r]);
    }
    float* ob = out + ((size_t)(b * S_) + qr0) * 128;
#pragma unroll
    for (int nt = 0; nt < 8; ++nt)
#pragma unroll
        for (int r = 0; r < 4; ++r)
            atomicAdd(&ob[(quad * 4 + r) * 128 + nt * 16 + l16], o[nt][r]);
}

__global__ __launch_bounds__(256) void norm_kernel(float* __restrict__ out,
                                                   const float* __restrict__ Lg) {
    int i = blockIdx.x * 256 + threadIdx.x;
    int row = i >> 5;
    floatx4 v = *(floatx4*)(out + (size_t)i * 4);
    float inv = 1.0f / Lg[row];
    v[0] *= inv; v[1] *= inv; v[2] *= inv; v[3] *= inv;
    *(floatx4*)(out + (size_t)i * 4) = v;
}

extern "C" void kernel_launch(void* const* d_in, const int* in_sizes, int n_in,
                              void* d_out, int out_size, void* d_ws, size_t ws_size,
                              hipStream_t stream) {
    const float* qkv = (const float*)d_in[0];
    float* out = (float*)d_out;
    const size_t MB = 1024 * 1024;
    const size_t KB = 1024;
    _Float16* Qh = (_Float16*)d_ws;                          // 8 MB
    _Float16* Kp = (_Float16*)((char*)d_ws + 8 * MB);        // 8 MB
    _Float16* Vp = (_Float16*)((char*)d_ws + 16 * MB);       // 8 MB

    const size_t ppart_bytes = (size_t)B_ * SLOTS_PER_B * 4096 * sizeof(_Float16); // 36 MB
    const size_t need = 25 * MB + ppart_bytes;

    if (ws_size >= need) {
        float*    Lpart = (float*)((char*)d_ws + 24 * MB);               // 576 KB
        int*      Cnt   = (int*)((char*)d_ws + 24 * MB + 640 * KB);      // 4 KB
        _Float16* Ppart = (_Float16*)((char*)d_ws + 25 * MB);            // 36 MB
        prep_kernel<<<dim3(256, B_), dim3(256), 0, stream>>>(qkv, Qh, Kp, Vp, Cnt);
        attn_part_kernel<<<dim3(64, 16), dim3(512), 0, stream>>>(Qh, Kp, Vp, Ppart, Lpart, Cnt, out);
    } else {
        prep_kernel<<<dim3(256, B_), dim3(256), 0, stream>>>(qkv, Qh, Kp, Vp, nullptr);
        float* Lg = (float*)((char*)d_ws + 24 * MB);             // 128 KB
        hipMemsetAsync(out, 0, (size_t)B_ * S_ * 128 * sizeof(float), stream);
        hipMemsetAsync(Lg, 0, (size_t)B_ * S_ * sizeof(float), stream);
        attn_atomic_kernel<<<dim3(64, 256), dim3(64), 0, stream>>>(Qh, Kp, Vp, out, Lg);
        norm_kernel<<<dim3(4096), dim3(256), 0, stream>>>(out, Lg);
    }
}

// Round 10
// 165.336 us; speedup vs baseline: 1.9714x; 1.9714x over previous
//
#include <hip/hip_runtime.h>
#include <math.h>

typedef _Float16 half8 __attribute__((ext_vector_type(8)));
typedef float floatx4 __attribute__((ext_vector_type(4)));
typedef float floatx2 __attribute__((ext_vector_type(2)));

#define B_ 8
#define S_ 4096
// scale = 1/sqrt(128) * log2(e): folded into Q so softmax exp is one v_exp_f32
#define SCALE_L2E 0.12751743008389106f
#define MASK_L2E  -14426.950408889634f   // -10000*log2(e): exp2 -> exact 0
#define L2_10K_OVER_128 0.10381025296522975f  // log2(10000)/128

#define PLD2 40   // P LDS row stride (halfs) = 80B, 16B-aligned; 32 cols + pad
#define KW  136   // prep K LDS row stride (halfs)
#define VW  24    // prep V^T LDS row stride (halfs)
#define OSTLD 136 // O-staging LDS row stride (halfs)
#define SLOTS_PER_B 576   // sum over qt32 of ceil(tiles/8)
#define NW 8      // waves per attn block
#define KVBUF 8192   // halfs per ring buffer: K 4096 | V 4096 (16KB)
#define NBUF 3       // 3-deep ring: single barrier per phase + depth-2 prefetch
#define POFF (NBUF * KVBUF)                       // 24576
#define POOL_HALFS (POFF + NW * 2 * 16 * PLD2)    // 34816 halfs = 69632 B

// units before q-block qt32 (chunks = floor(qt32/16)+1)
__device__ __forceinline__ int chunk_prefix(int qt32) {
    int g = qt32 >> 4;
    return qt32 + 8 * g * (g - 1) + (qt32 - (g << 4)) * g;
}

// async global->LDS, 16B per lane, wave-uniform LDS base (HW adds lane*16)
__device__ __forceinline__ void glds16(const _Float16* src, _Float16* dst) {
    __builtin_amdgcn_global_load_lds((const __attribute__((address_space(1))) void*)src,
                                     (__attribute__((address_space(3))) void*)dst, 16, 0, 0);
}

// ---------------- kernel 1: prep (R5 layouts, unchanged) ----------------
// grid (256, 8), block 256: 16 seq rows per block.
//  Qh: RoPE(Q)*SCALE_L2E fp16 row-major [b][s][d]
//  Kp: frag-major: chunk(b,s16,c)[lane=quad*16+n][j] = K[s16*16+n][c*32+quad*8+j]
//  Vp: frag-major: chunk(b,kt,c2,nt)[lane=quad*16+n][j] = V[kt*64+c2*32+quad*8+j][nt*16+n]
__global__ __launch_bounds__(256) void prep_kernel(const float* __restrict__ qkv,
                                                   _Float16* __restrict__ Qh,
                                                   _Float16* __restrict__ Kp,
                                                   _Float16* __restrict__ Vp) {
    __shared__ __align__(16) _Float16 Kl[16][KW];
    __shared__ __align__(16) _Float16 Vt[128][VW];
    const int tid = threadIdx.x;
    const int b   = blockIdx.y;
    const int s0  = blockIdx.x * 16;

#pragma unroll
    for (int it = 0; it < 4; ++it) {
        int idx = tid + it * 256;
        int i = idx & 63, sr = idx >> 6, s = s0 + sr;
        const float* base = qkv + ((size_t)(b * S_ + s)) * 384 + 2 * i;
        floatx2 q2 = *(const floatx2*)base;
        floatx2 k2 = *(const floatx2*)(base + 128);
        float inv = exp2f(-(float)(2 * i) * L2_10K_OVER_128);
        float ang = (float)s * inv;
        float sn, cs;
        __sincosf(ang, &sn, &cs);
        size_t oq = ((size_t)(b * S_ + s)) * 128 + 2 * i;
        Qh[oq]     = (_Float16)((q2[0] * cs - q2[1] * sn) * SCALE_L2E);
        Qh[oq + 1] = (_Float16)((q2[0] * sn + q2[1] * cs) * SCALE_L2E);
        Kl[sr][2 * i]     = (_Float16)(k2[0] * cs - k2[1] * sn);
        Kl[sr][2 * i + 1] = (_Float16)(k2[0] * sn + k2[1] * cs);
    }
#pragma unroll
    for (int it = 0; it < 2; ++it) {
        int idx = tid + it * 256;
        int c = idx & 31, sr = idx >> 5;
        floatx4 v = *(const floatx4*)(qkv + ((size_t)(b * S_ + s0 + sr)) * 384 + 256 + c * 4);
#pragma unroll
        for (int j = 0; j < 4; ++j) Vt[c * 4 + j][sr] = (_Float16)v[j];
    }
    __syncthreads();

    {   // K frag-major out
        int c = tid >> 6, lane = tid & 63;
        int quad = lane >> 4, n = lane & 15;
        half8 val = *(const half8*)&Kl[n][c * 32 + quad * 8];
        int s16 = s0 >> 4;
        *(half8*)(Kp + (((size_t)(b * 256 + s16) * 4 + c) * 64 + lane) * 8) = val;
    }
    {   // V frag-major out
        int kt = s0 >> 6, c2 = (s0 >> 5) & 1, qp = (s0 >> 4) & 1;
        int nt = tid >> 5, lq = (tid >> 4) & 1, n = tid & 15;
        int quad = qp * 2 + lq;
        int lane = quad * 16 + n;
        half8 val = *(const half8*)&Vt[nt * 16 + n][lq * 8];
        *(half8*)(Vp + ((((size_t)(b * 64 + kt) * 2 + c2) * 8 + nt) * 64 + lane) * 8) = val;
    }
}

// ---------------- kernel 2a: split-K flash, cooperative-staged ----------------
// R5 structure exactly (best verified 73.2us): grid (64,16) x=(b,chunk) -> XCD b
// holds batch b's K/V in its L2; block 512 = 8 waves sharing (b,chunk); 3-buffer
// ring, 1 barrier/phase, depth-2 prefetch, counted vmcnt(2).
// R10 deltas: (1) s_setprio(1) around MFMA clusters (T5; cross-block wave
// diversity at 2 blocks/CU); (2) single-chunk fast path: waves owning the FULL
// K-span (chunk==0 && kt_max<=7, qt32<=15) normalize in-register and write f32
// out directly -- no Ppart/Lpart, and reduce_kernel skips those units.
// NOTE (R9 lesson): NO __threadfence here -- device-scope fences force L2
// writeback on non-coherent XCDs and destroyed the K/V working set (73->255us).
__global__ __launch_bounds__(512) void attn_part_kernel(const _Float16* __restrict__ Qh,
                                                        const _Float16* __restrict__ Kp,
                                                        const _Float16* __restrict__ Vp,
                                                        _Float16* __restrict__ Ppart,
                                                        float* __restrict__ Lpart,
                                                        float* __restrict__ out) {
    __shared__ __align__(16) _Float16 POOL[POOL_HALFS];

    const int tid  = threadIdx.x;
    const int w    = tid >> 6;
    const int lane = tid & 63;
    const int quad = lane >> 4;
    const int l16  = lane & 15;
    const int b     = blockIdx.x & 7;
    const int chunk = blockIdx.x >> 3;
    const int c0    = chunk * 8;

    const int qt32_top  = 127 - blockIdx.y * 8;          // wave 0's qt32 (largest in block)
    const int ktmax_blk = (qt32_top * 32 + 31) >> 6;
    if (c0 > ktmax_blk) return;                          // uniform: whole block exits
    const int kend_blk  = min(ktmax_blk, c0 + 7);

    const int qt32   = qt32_top - w;
    const int qr0    = qt32 * 32;
    const int kt_max = (qr0 + 31) >> 6;
    const bool has_work = (c0 <= kt_max);
    const int kend   = min(kt_max, c0 + 7);
    const int slot   = b * SLOTS_PER_B + chunk_prefix(qt32) + chunk;
    _Float16* Pw = POOL + POFF + w * (2 * 16 * PLD2);

    half8 aq[2][4];
#pragma unroll
    for (int tile = 0; tile < 2; ++tile) {
        const _Float16* Qb = Qh + ((size_t)(b * S_) + qr0 + tile * 16 + l16) * 128;
#pragma unroll
        for (int c = 0; c < 4; ++c) aq[tile][c] = *(const half8*)(Qb + c * 32 + quad * 8);
    }

    floatx4 o[2][8];
#pragma unroll
    for (int tile = 0; tile < 2; ++tile)
#pragma unroll
        for (int i = 0; i < 8; ++i) o[tile][i] = (floatx4){0.f, 0.f, 0.f, 0.f};
    float rsum[2][4] = {{0.f, 0.f, 0.f, 0.f}, {0.f, 0.f, 0.f, 0.f}};

    const _Float16* Kb = Kp + (size_t)b * 524288;
    const _Float16* Vb = Vp + (size_t)b * 524288;

    const int ht0    = 2 * c0;            // half-tile index = kt*2 + h; K/V halfs at ht*4096
    const int ht_end = 2 * kend_blk + 1;  // >= ht0+1 always

    // stage half-tile ht_ into ring buffer ht_%3 (wave w moves 1KB K + 1KB V)
#define STAGE(ht_)                                                                \
    do {                                                                          \
        const _Float16* ks_ = Kb + (size_t)(ht_) * 4096 + w * 512 + lane * 8;     \
        const _Float16* vs_ = Vb + (size_t)(ht_) * 4096 + w * 512 + lane * 8;     \
        _Float16* d_ = POOL + ((ht_) % NBUF) * KVBUF + w * 512;                   \
        glds16(ks_, d_);                                                          \
        glds16(vs_, d_ + 4096);                                                   \
    } while (0)

    // prologue: stage the first two half-tiles (4 loads in flight)
    STAGE(ht0);
    STAGE(ht0 + 1);

    for (int ht = ht0; ht <= ht_end; ++ht) {
        if (ht < ht_end) {
            asm volatile("s_waitcnt vmcnt(2)" ::: "memory");  // buf[ht%3] loads retired
        } else {
            asm volatile("s_waitcnt vmcnt(0)" ::: "memory");
        }
        __builtin_amdgcn_s_barrier();
        if (ht + 2 <= ht_end) STAGE(ht + 2);

        const int kt = ht >> 1, h = ht & 1;
        if (has_work && kt <= kend) {
            const _Float16* Klds = POOL + (ht % NBUF) * KVBUF;
            const _Float16* Vlds = Klds + 4096;

            // S(:, local 32 cols) = Q K^T
            floatx4 s4[2][2];
#pragma unroll
            for (int tl = 0; tl < 2; ++tl) {
                half8 bk[4];
#pragma unroll
                for (int c = 0; c < 4; ++c)
                    bk[c] = *(const half8*)&Klds[((tl * 4 + c) * 64 + lane) * 8];
                floatx4 a0 = (floatx4){0.f, 0.f, 0.f, 0.f};
                floatx4 a1 = (floatx4){0.f, 0.f, 0.f, 0.f};
                __builtin_amdgcn_s_setprio(1);
#pragma unroll
                for (int c = 0; c < 4; ++c) {
                    a0 = __builtin_amdgcn_mfma_f32_16x16x32_f16(aq[0][c], bk[c], a0, 0, 0, 0);
                    a1 = __builtin_amdgcn_mfma_f32_16x16x32_f16(aq[1][c], bk[c], a1, 0, 0, 0);
                }
                __builtin_amdgcn_s_setprio(0);
                s4[0][tl] = a0; s4[1][tl] = a1;
            }

            // V frags: issue EARLY (no in-phase dependency) so ds_read latency
            // hides under the mask/exp/P-write VALU section below.
            half8 vf[8];
#pragma unroll
            for (int nt = 0; nt < 8; ++nt)
                vf[nt] = *(const half8*)&Vlds[(nt * 64 + lane) * 8];

            if (kt == kt_max) {  // causal mask, diagonal tile only
#pragma unroll
                for (int tile = 0; tile < 2; ++tile)
#pragma unroll
                    for (int tl = 0; tl < 2; ++tl)
#pragma unroll
                        for (int r = 0; r < 4; ++r) {
                            int kcol = kt * 64 + h * 32 + tl * 16 + l16;
                            int qr   = qr0 + tile * 16 + quad * 4 + r;
                            if (kcol > qr) s4[tile][tl][r] += MASK_L2E;
                        }
            }

            // p = exp2(s), lane-local l, P -> per-wave LDS (C->A layout transform)
#pragma unroll
            for (int tile = 0; tile < 2; ++tile)
#pragma unroll
                for (int tl = 0; tl < 2; ++tl)
#pragma unroll
                    for (int r = 0; r < 4; ++r) {
                        float p = __builtin_amdgcn_exp2f(s4[tile][tl][r]);
                        rsum[tile][r] += p;
                        Pw[tile * (16 * PLD2) + (quad * 4 + r) * PLD2 + tl * 16 + l16] = (_Float16)p;
                    }

            // O += P V  (this phase's 32 k-rows)
#pragma unroll
            for (int tile = 0; tile < 2; ++tile) {
                half8 ap = *(const half8*)&Pw[tile * (16 * PLD2) + l16 * PLD2 + quad * 8];
                __builtin_amdgcn_s_setprio(1);
#pragma unroll
                for (int nt = 0; nt < 8; ++nt)
                    o[tile][nt] = __builtin_amdgcn_mfma_f32_16x16x32_f16(ap, vf[nt], o[tile][nt], 0, 0, 0);
                __builtin_amdgcn_s_setprio(0);
            }
        }
    }
#undef STAGE

    // protect POOL reuse below: all waves done reading the ring
    __builtin_amdgcn_s_barrier();

    if (!has_work) return;

    // row sums: reduce over l16 via shfl_xor -> every lane holds its row's full sum
#pragma unroll
    for (int off = 1; off <= 8; off <<= 1)
#pragma unroll
        for (int tile = 0; tile < 2; ++tile)
#pragma unroll
            for (int r = 0; r < 4; ++r)
                rsum[tile][r] += __shfl_xor(rsum[tile][r], off, 64);

    const bool single = (chunk == 0) && (kt_max <= 7);   // wave owns the FULL K-span
    _Float16* Ost = POOL + w * (POOL_HALFS / NW);        // per-wave slice (>=2176 halfs)

    if (single) {
        // normalize in-register, stage fp16, write f32 out directly (no partials)
        float inv[2][4];
#pragma unroll
        for (int tile = 0; tile < 2; ++tile)
#pragma unroll
            for (int r = 0; r < 4; ++r) inv[tile][r] = 1.0f / rsum[tile][r];
        float* ob = out + ((size_t)(b * S_) + qr0) * 128;
#pragma unroll
        for (int tile = 0; tile < 2; ++tile) {
#pragma unroll
            for (int nt = 0; nt < 8; ++nt)
#pragma unroll
                for (int r = 0; r < 4; ++r)
                    Ost[(quad * 4 + r) * OSTLD + nt * 16 + l16] = (_Float16)(o[tile][nt][r] * inv[tile][r]);
#pragma unroll
            for (int i = 0; i < 4; ++i) {
                int idx = lane + i * 64;    // row=idx>>4 (0..15), colgrp=idx&15
                half8 v = *(const half8*)&Ost[(idx >> 4) * OSTLD + (idx & 15) * 8];
                float* op = ob + ((size_t)(tile * 16 + (idx >> 4)) * 128 + (idx & 15) * 8);
                *(floatx4*)op       = (floatx4){(float)v[0], (float)v[1], (float)v[2], (float)v[3]};
                *(floatx4*)(op + 4) = (floatx4){(float)v[4], (float)v[5], (float)v[6], (float)v[7]};
            }
        }
        return;
    }

    // l partials: plain store (no atomics)
    if (l16 == 0) {
#pragma unroll
        for (int tile = 0; tile < 2; ++tile)
#pragma unroll
            for (int r = 0; r < 4; ++r)
                Lpart[(size_t)slot * 32 + tile * 16 + quad * 4 + r] = rsum[tile][r];
    }

    // O partial: C-layout -> LDS fp16 staging -> coalesced 16B streaming stores
    _Float16* pp = Ppart + (size_t)slot * 4096;
#pragma unroll
    for (int tile = 0; tile < 2; ++tile) {
#pragma unroll
        for (int nt = 0; nt < 8; ++nt)
#pragma unroll
            for (int r = 0; r < 4; ++r)
                Ost[(quad * 4 + r) * OSTLD + nt * 16 + l16] = (_Float16)o[tile][nt][r];
#pragma unroll
        for (int i = 0; i < 4; ++i) {
            int idx = lane + i * 64;        // half8-group: row=idx>>4, colgrp=idx&15
            half8 v = *(const half8*)&Ost[(idx >> 4) * OSTLD + (idx & 15) * 8];
            *(half8*)(pp + ((size_t)tile * 256 + idx) * 8) = v;
        }
    }
}

// ---------------- kernel 2b: reduce partials + normalize ----------------
// grid 1024 (= B x 128 q-blocks), block 256. Sums <=8 fp16 partials, divides by l.
// Units with nch==1 (qt32<=15) were written directly by attn -> skip.
__global__ __launch_bounds__(256) void reduce_kernel(const _Float16* __restrict__ Ppart,
                                                     const float* __restrict__ Lpart,
                                                     float* __restrict__ out) {
    const int bid  = blockIdx.x;
    const int b    = bid >> 7;
    const int qt32 = bid & 127;
    if (qt32 <= 15) return;                 // single-chunk: attn wrote out directly
    const int qr0  = qt32 * 32;
    const int nch  = (((qr0 + 31) >> 6) >> 3) + 1;
    const int slot0 = b * SLOTS_PER_B + chunk_prefix(qt32);
    const _Float16* pp = Ppart + (size_t)slot0 * 4096;
    const float* lp = Lpart + (size_t)slot0 * 32;
    const int tid = threadIdx.x;

#pragma unroll
    for (int j = 0; j < 2; ++j) {
        int idx = tid + j * 256;            // half8 group 0..511
        int row = idx >> 4;
        float acc[8] = {0.f, 0.f, 0.f, 0.f, 0.f, 0.f, 0.f, 0.f};
        float l = 0.f;
        for (int c = 0; c < nch; ++c) {
            half8 v = *(const half8*)(pp + (size_t)c * 4096 + (size_t)idx * 8);
#pragma unroll
            for (int k = 0; k < 8; ++k) acc[k] += (float)v[k];
            l += lp[c * 32 + row];
        }
        float inv = 1.0f / l;
        float* ob = out + ((size_t)(b * S_) + qr0) * 128 + (size_t)idx * 8;
        floatx4 o0 = (floatx4){acc[0] * inv, acc[1] * inv, acc[2] * inv, acc[3] * inv};
        floatx4 o1 = (floatx4){acc[4] * inv, acc[5] * inv, acc[6] * inv, acc[7] * inv};
        *(floatx4*)ob = o0;
        *(floatx4*)(ob + 4) = o1;
    }
}

// ---------------- fallback (ws too small): R5 atomic path ----------------
#define PLD 72
__global__ __launch_bounds__(64) void attn_atomic_kernel(const _Float16* __restrict__ Qh,
                                                         const _Float16* __restrict__ Kp,
                                                         const _Float16* __restrict__ Vp,
                                                         float* __restrict__ out,
                                                         float* __restrict__ Lg) {
    __shared__ __align__(16) _Float16 Pl[2][16 * PLD];
    const int lane = threadIdx.x, quad = lane >> 4, l16 = lane & 15;
    const int b = blockIdx.x & 7, chunk = blockIdx.x >> 3;
    const int qt = 255 - blockIdx.y, qr0 = qt * 16;
    const int kt_max = qt >> 2, c0 = chunk * 8;
    if (c0 > kt_max) return;
    const int kend = min(kt_max, c0 + 7);
    const _Float16* Qb = Qh + ((size_t)(b * S_) + qr0 + l16) * 128;
    half8 aq[4];
#pragma unroll
    for (int c = 0; c < 4; ++c) aq[c] = *(const half8*)(Qb + c * 32 + quad * 8);
    floatx4 o[8];
#pragma unroll
    for (int i = 0; i < 8; ++i) o[i] = (floatx4){0.f, 0.f, 0.f, 0.f};
    float rsum[4] = {0.f, 0.f, 0.f, 0.f};
    const _Float16* Kb = Kp + (size_t)b * 524288;
    const _Float16* Vb = Vp + (size_t)b * 524288;
    for (int kt = c0; kt <= kend; ++kt) {
        half8 vf[2][8];
#pragma unroll
        for (int c2 = 0; c2 < 2; ++c2)
#pragma unroll
            for (int nt = 0; nt < 8; ++nt)
                vf[c2][nt] = *(const half8*)(Vb + (((size_t)(kt * 2 + c2) * 8 + nt) * 64 + lane) * 8);
        floatx4 s4[4];
#pragma unroll
        for (int t = 0; t < 4; ++t) {
            const _Float16* kp = Kb + ((size_t)((kt * 4 + t) * 4) * 64 + lane) * 8;
            floatx4 acc = (floatx4){0.f, 0.f, 0.f, 0.f};
#pragma unroll
            for (int c = 0; c < 4; ++c) {
                half8 bk = *(const half8*)(kp + c * 512);
                acc = __builtin_amdgcn_mfma_f32_16x16x32_f16(aq[c], bk, acc, 0, 0, 0);
            }
            s4[t] = acc;
        }
        if (kt == kt_max) {
#pragma unroll
            for (int t = 0; t < 4; ++t)
#pragma unroll
                for (int r = 0; r < 4; ++r) {
                    int kcol = kt * 64 + t * 16 + l16;
                    int qr = qr0 + quad * 4 + r;
                    if (kcol > qr) s4[t][r] += MASK_L2E;
                }
        }
        const int buf = kt & 1;
#pragma unroll
        for (int t = 0; t < 4; ++t)
#pragma unroll
            for (int r = 0; r < 4; ++r) {
                float p = __builtin_amdgcn_exp2f(s4[t][r]);
                rsum[r] += p;
                Pl[buf][(quad * 4 + r) * PLD + t * 16 + l16] = (_Float16)p;
            }
#pragma unroll
        for (int c2 = 0; c2 < 2; ++c2) {
            half8 ap = *(const half8*)&Pl[buf][l16 * PLD + c2 * 32 + quad * 8];
#pragma unroll
            for (int nt = 0; nt < 8; ++nt)
                o[nt] = __builtin_amdgcn_mfma_f32_16x16x32_f16(ap, vf[c2][nt], o[nt], 0, 0, 0);
        }
    }
#pragma unroll
    for (int off = 1; off <= 8; off <<= 1)
#pragma unroll
        for (int r = 0; r < 4; ++r)
            rsum[r] += __shfl_xor(rsum[r], off, 64);
    if (l16 == 0) {
#pragma unroll
        for (int r = 0; r < 4; ++r)
            atomicAdd(&Lg[(size_t)(b * S_) + qr0 + quad * 4 + r], rsum[r]);
    }
    float* ob = out + ((size_t)(b * S_) + qr0) * 128;
#pragma unroll
    for (int nt = 0; nt < 8; ++nt)
#pragma unroll
        for (int r = 0; r < 4; ++r)
            atomicAdd(&ob[(quad * 4 + r) * 128 + nt * 16 + l16], o[nt][r]);
}

__global__ __launch_bounds__(256) void norm_kernel(float* __restrict__ out,
                                                   const float* __restrict__ Lg) {
    int i = blockIdx.x * 256 + threadIdx.x;
    int row = i >> 5;
    floatx4 v = *(floatx4*)(out + (size_t)i * 4);
    float inv = 1.0f / Lg[row];
    v[0] *= inv; v[1] *= inv; v[2] *= inv; v[3] *= inv;
    *(floatx4*)(out + (size_t)i * 4) = v;
}

extern "C" void kernel_launch(void* const* d_in, const int* in_sizes, int n_in,
                              void* d_out, int out_size, void* d_ws, size_t ws_size,
                              hipStream_t stream) {
    const float* qkv = (const float*)d_in[0];
    float* out = (float*)d_out;
    const size_t MB = 1024 * 1024;
    _Float16* Qh = (_Float16*)d_ws;                          // 8 MB
    _Float16* Kp = (_Float16*)((char*)d_ws + 8 * MB);        // 8 MB
    _Float16* Vp = (_Float16*)((char*)d_ws + 16 * MB);       // 8 MB

    const size_t ppart_bytes = (size_t)B_ * SLOTS_PER_B * 4096 * sizeof(_Float16); // 36 MB
    const size_t need = 25 * MB + ppart_bytes;

    prep_kernel<<<dim3(256, B_), dim3(256), 0, stream>>>(qkv, Qh, Kp, Vp);

    if (ws_size >= need) {
        float*    Lpart = (float*)((char*)d_ws + 24 * MB);       // 576 KB
        _Float16* Ppart = (_Float16*)((char*)d_ws + 25 * MB);    // 36 MB
        attn_part_kernel<<<dim3(64, 16), dim3(512), 0, stream>>>(Qh, Kp, Vp, Ppart, Lpart, out);
        reduce_kernel<<<dim3(1024), dim3(256), 0, stream>>>(Ppart, Lpart, out);
    } else {
        float* Lg = (float*)((char*)d_ws + 24 * MB);             // 128 KB
        hipMemsetAsync(out, 0, (size_t)B_ * S_ * 128 * sizeof(float), stream);
        hipMemsetAsync(Lg, 0, (size_t)B_ * S_ * sizeof(float), stream);
        attn_atomic_kernel<<<dim3(64, 256), dim3(64), 0, stream>>>(Qh, Kp, Vp, out, Lg);
        norm_kernel<<<dim3(4096), dim3(256), 0, stream>>>(out, Lg);
    }
}

// Round 11
// 152.547 us; speedup vs baseline: 2.1366x; 1.0838x over previous
//
#include <hip/hip_runtime.h>
#include <math.h>

typedef _Float16 half8 __attribute__((ext_vector_type(8)));
typedef float floatx4 __attribute__((ext_vector_type(4)));
typedef float floatx16 __attribute__((ext_vector_type(16)));
typedef float floatx2 __attribute__((ext_vector_type(2)));

#define B_ 8
#define S_ 4096
// scale = 1/sqrt(128) * log2(e): folded into Q so softmax exp is one v_exp_f32
#define SCALE_L2E 0.12751743008389106f
#define MASK_L2E  -14426.950408889634f   // -10000*log2(e): exp2 -> exact 0
#define L2_10K_OVER_128 0.10381025296522975f  // log2(10000)/128

#define KW  136   // prep K LDS row stride (halfs)
#define VW  24    // prep V^T LDS row stride (halfs)
#define OSTLD 136 // O-staging LDS row stride (halfs)
#define SLOTS_PER_B 576   // sum over qt32 of ceil(tiles/8)
#define NW 8      // waves per attn block
#define KVBUF 8192   // halfs per ring buffer: K 4096 | V 4096 (16KB)
#define NBUF 3       // 3-deep ring: single barrier per phase + depth-2 prefetch
#define POOL_HALFS (NBUF * KVBUF)   // 24576 halfs = 49152 B

// units before q-block qt32 (chunks = floor(qt32/16)+1)
__device__ __forceinline__ int chunk_prefix(int qt32) {
    int g = qt32 >> 4;
    return qt32 + 8 * g * (g - 1) + (qt32 - (g << 4)) * g;
}

// async global->LDS, 16B per lane, wave-uniform LDS base (HW adds lane*16)
__device__ __forceinline__ void glds16(const _Float16* src, _Float16* dst) {
    __builtin_amdgcn_global_load_lds((const __attribute__((address_space(1))) void*)src,
                                     (__attribute__((address_space(3))) void*)dst, 16, 0, 0);
}

// pack two f32 -> one u32 of two fp16 (low half = first arg)
__device__ __forceinline__ unsigned pack2(float a, float b) {
    union { _Float16 h[2]; unsigned u; } x;
    x.h[0] = (_Float16)a; x.h[1] = (_Float16)b;
    return x.u;
}

// ---------------- kernel 1: prep (32x32-fragment layouts) ----------------
// grid (256, 8), block 256: 16 seq rows per block.
//  Qh: RoPE(Q)*SCALE_L2E fp16 row-major [b][s][d]  (unchanged)
//  Kp32: per 32-row half-tile ht, d-step c(0..7):
//        chunk(b,ht,c)[lane][j] = K[ht*32 + (lane&31)][c*16 + (lane>>5)*8 + j]
//        -> direct A-frag for mfma_32x32x16 (M=k-rows)
//  Vp32: per ht, k-step s(0..1), d-tile n(0..3):
//        chunk(b,ht,s*4+n)[lane][j] = V[ht*32 + s*16 + (lane>>5)*8 + j][n*32 + (lane&31)]
//        -> direct B-frag for PV mfma_32x32x16 (N=d)
__global__ __launch_bounds__(256) void prep_kernel(const float* __restrict__ qkv,
                                                   _Float16* __restrict__ Qh,
                                                   _Float16* __restrict__ Kp,
                                                   _Float16* __restrict__ Vp) {
    __shared__ __align__(16) _Float16 Kl[16][KW];
    __shared__ __align__(16) _Float16 Vt[128][VW];
    const int tid = threadIdx.x;
    const int b   = blockIdx.y;
    const int s0  = blockIdx.x * 16;

#pragma unroll
    for (int it = 0; it < 4; ++it) {
        int idx = tid + it * 256;
        int i = idx & 63, sr = idx >> 6, s = s0 + sr;
        const float* base = qkv + ((size_t)(b * S_ + s)) * 384 + 2 * i;
        floatx2 q2 = *(const floatx2*)base;
        floatx2 k2 = *(const floatx2*)(base + 128);
        float inv = exp2f(-(float)(2 * i) * L2_10K_OVER_128);
        float ang = (float)s * inv;
        float sn, cs;
        __sincosf(ang, &sn, &cs);
        size_t oq = ((size_t)(b * S_ + s)) * 128 + 2 * i;
        Qh[oq]     = (_Float16)((q2[0] * cs - q2[1] * sn) * SCALE_L2E);
        Qh[oq + 1] = (_Float16)((q2[0] * sn + q2[1] * cs) * SCALE_L2E);
        Kl[sr][2 * i]     = (_Float16)(k2[0] * cs - k2[1] * sn);
        Kl[sr][2 * i + 1] = (_Float16)(k2[0] * sn + k2[1] * cs);
    }
#pragma unroll
    for (int it = 0; it < 2; ++it) {
        int idx = tid + it * 256;
        int c = idx & 31, sr = idx >> 5;
        floatx4 v = *(const floatx4*)(qkv + ((size_t)(b * S_ + s0 + sr)) * 384 + 256 + c * 4);
#pragma unroll
        for (int j = 0; j < 4; ++j) Vt[c * 4 + j][sr] = (_Float16)v[j];
    }
    __syncthreads();

    const int ht = s0 >> 5;
    {   // K 32x32 A-frag-major out: tid -> g = d-group(0..15), sr = row(0..15)
        int g = tid >> 4, sr = tid & 15;
        int r = s0 + sr;
        int c = g >> 1, dh = g & 1;
        int l = (r & 31) + (dh << 5);
        half8 val = *(const half8*)&Kl[sr][g * 8];
        *(half8*)(Kp + (((size_t)(b * 128 + ht) * 8 + c) * 64 + l) * 8) = val;
    }
    {   // V 32x32 B-frag-major out: tid -> n = d-tile(0..3), l = lane(0..63)
        int n = tid >> 6, l = tid & 63;
        int sh = (s0 >> 4) & 1;             // which k-step half of ht this block covers
        half8 val = *(const half8*)&Vt[n * 32 + (l & 31)][(l >> 5) * 8];
        *(half8*)(Vp + (((size_t)(b * 128 + ht) * 8 + sh * 4 + n) * 64 + l) * 8) = val;
    }
}

// ---------------- kernel 2a: split-K flash, 32x32 MFMA + in-register P ----------------
// Skeleton = R5 (best verified 73.2us): grid (64,16) x=(b,chunk) -> XCD-b L2
// affinity; block 512 = 8 waves sharing (b,chunk); 3-buffer ring, 1 barrier/
// phase, depth-2 prefetch, counted vmcnt(2).
// R11: swapped QK^T with mfma_f32_32x32x16_f16 (C: q=lane&31, k=(r&3)+8(r>>2)
// +4(lane>>5)) -> exp2 -> pack -> 4x v_permlane32_swap (pure VALU cross-lane,
// NOT LDS like shfl/bpermute) builds the PV A-frag in registers. The P LDS
// round-trip (16 ds_write + lgkm drain + 2 ds_read_b128, on the serial path of
// EVERY phase since R0; source of the constant 679,936 bank-conflict count) is
// gone. No setprio (R10: -4us on lockstep waves).
__global__ __launch_bounds__(512) void attn_part_kernel(const _Float16* __restrict__ Qh,
                                                        const _Float16* __restrict__ Kp,
                                                        const _Float16* __restrict__ Vp,
                                                        _Float16* __restrict__ Ppart,
                                                        float* __restrict__ Lpart) {
    __shared__ __align__(16) _Float16 POOL[POOL_HALFS];

    const int tid  = threadIdx.x;
    const int w    = tid >> 6;
    const int lane = tid & 63;
    const int l31  = lane & 31;
    const int lh   = lane >> 5;
    const int b     = blockIdx.x & 7;
    const int chunk = blockIdx.x >> 3;
    const int c0    = chunk * 8;

    const int qt32_top  = 127 - blockIdx.y * 8;          // wave 0's qt32 (largest in block)
    const int ktmax_blk = (qt32_top * 32 + 31) >> 6;
    if (c0 > ktmax_blk) return;                          // uniform: whole block exits
    const int kend_blk  = min(ktmax_blk, c0 + 7);

    const int qt32   = qt32_top - w;
    const int qr0    = qt32 * 32;
    const int kt_max = (qr0 + 31) >> 6;
    const bool has_work = (c0 <= kt_max);
    const int kend   = min(kt_max, c0 + 7);
    const int slot   = b * SLOTS_PER_B + chunk_prefix(qt32) + chunk;

    // Q B-frags (col q = l31, d = c*16 + lh*8 + j): contiguous half8 from row-major Qh
    half8 aq[8];
    {
        const _Float16* Qb = Qh + ((size_t)(b * S_) + qr0 + l31) * 128 + lh * 8;
#pragma unroll
        for (int c = 0; c < 8; ++c) aq[c] = *(const half8*)(Qb + c * 16);
    }

    floatx16 o[4];
#pragma unroll
    for (int n = 0; n < 4; ++n)
#pragma unroll
        for (int r = 0; r < 16; ++r) o[n][r] = 0.f;
    float rsum = 0.f;   // per-lane partial row-sum for q = l31 (this lane-half's k's)

    const _Float16* Kb = Kp + (size_t)b * 524288;
    const _Float16* Vb = Vp + (size_t)b * 524288;

    const int ht0    = 2 * c0;            // half-tile index = kt*2 + h; K/V halfs at ht*4096
    const int ht_end = 2 * kend_blk + 1;  // >= ht0+1 always

    // stage half-tile ht_ into ring buffer ht_%3 (wave w moves 1KB K + 1KB V)
#define STAGE(ht_)                                                                \
    do {                                                                          \
        const _Float16* ks_ = Kb + (size_t)(ht_) * 4096 + w * 512 + lane * 8;     \
        const _Float16* vs_ = Vb + (size_t)(ht_) * 4096 + w * 512 + lane * 8;     \
        _Float16* d_ = POOL + ((ht_) % NBUF) * KVBUF + w * 512;                   \
        glds16(ks_, d_);                                                          \
        glds16(vs_, d_ + 4096);                                                   \
    } while (0)

    // prologue: stage the first two half-tiles (4 loads in flight)
    STAGE(ht0);
    STAGE(ht0 + 1);

    for (int ht = ht0; ht <= ht_end; ++ht) {
        if (ht < ht_end) {
            asm volatile("s_waitcnt vmcnt(2)" ::: "memory");  // buf[ht%3] loads retired
        } else {
            asm volatile("s_waitcnt vmcnt(0)" ::: "memory");
        }
        __builtin_amdgcn_s_barrier();
        if (ht + 2 <= ht_end) STAGE(ht + 2);

        const int kt = ht >> 1;
        if (has_work && kt <= kend) {
            const _Float16* Klds = POOL + (ht % NBUF) * KVBUF;
            const _Float16* Vlds = Klds + 4096;

            // S^T = K Q^T over d=0..127 (8 accumulating 32x32x16 MFMAs)
            floatx16 Cs;
#pragma unroll
            for (int r = 0; r < 16; ++r) Cs[r] = 0.f;
#pragma unroll
            for (int c = 0; c < 8; ++c) {
                half8 ak = *(const half8*)&Klds[(c * 64 + lane) * 8];
                Cs = __builtin_amdgcn_mfma_f32_32x32x16_f16(ak, aq[c], Cs, 0, 0, 0);
            }

            // V B-frags: issue EARLY so ds_read latency hides under the VALU section
            half8 bv[8];
#pragma unroll
            for (int i = 0; i < 8; ++i)
                bv[i] = *(const half8*)&Vlds[(i * 64 + lane) * 8];

            if (kt == kt_max) {  // causal mask (diagonal half-tiles only)
#pragma unroll
                for (int r = 0; r < 16; ++r) {
                    int kl = (r & 3) + 8 * (r >> 2) + 4 * lh;
                    if (ht * 32 + kl > qr0 + l31) Cs[r] += MASK_L2E;
                }
            }

            // exp2 -> pack f16 pairs -> permlane32_swap builds PV A-frags in regs
            float e[16];
#pragma unroll
            for (int r = 0; r < 16; ++r) {
                e[r] = __builtin_amdgcn_exp2f(Cs[r]);
                rsum += e[r];
            }
            unsigned A0 = pack2(e[0], e[1]),  B0 = pack2(e[2], e[3]);
            unsigned C0 = pack2(e[4], e[5]),  D0 = pack2(e[6], e[7]);
            unsigned A1 = pack2(e[8], e[9]),  B1 = pack2(e[10], e[11]);
            unsigned C1 = pack2(e[12], e[13]), D1 = pack2(e[14], e[15]);
            // D.hi <-> S.lo : after swap(X,Y): X = [X_lo | Y_lo_from_lo_lanes],
            // Y = [X_hi_from_hi_lanes | Y_hi]. Verified word map for A-frag
            // (q=l31, k=step*16+lh*8+j) in all four lane-half x step quadrants.
            asm("v_permlane32_swap_b32 %0, %1" : "+v"(A0), "+v"(C0));
            asm("v_permlane32_swap_b32 %0, %1" : "+v"(B0), "+v"(D0));
            asm("v_permlane32_swap_b32 %0, %1" : "+v"(A1), "+v"(C1));
            asm("v_permlane32_swap_b32 %0, %1" : "+v"(B1), "+v"(D1));
            union { unsigned u[4]; half8 v; } pa0, pa1;
            pa0.u[0] = A0; pa0.u[1] = B0; pa0.u[2] = C0; pa0.u[3] = D0;
            pa1.u[0] = A1; pa1.u[1] = B1; pa1.u[2] = C1; pa1.u[3] = D1;

            // O += P V  (2 k-steps x 4 d-tiles)
#pragma unroll
            for (int n = 0; n < 4; ++n)
                o[n] = __builtin_amdgcn_mfma_f32_32x32x16_f16(pa0.v, bv[n], o[n], 0, 0, 0);
#pragma unroll
            for (int n = 0; n < 4; ++n)
                o[n] = __builtin_amdgcn_mfma_f32_32x32x16_f16(pa1.v, bv[4 + n], o[n], 0, 0, 0);
        }
    }
#undef STAGE

    // protect POOL reuse below: all waves done reading the ring
    __builtin_amdgcn_s_barrier();

    if (!has_work) return;

    // row sums: lane-half pair (l, l+32) covers all 32 k per phase -> one xor-32 add
    rsum += __shfl_xor(rsum, 32, 64);
    if (lane < 32) Lpart[(size_t)slot * 32 + lane] = rsum;

    // O partial: C rows q = (r&3)+8*(r>>2)+4*lh, cols n*32+l31 -> LDS fp16
    // staging (16 rows/pass, per-wave slice) -> coalesced 16B streaming stores.
    _Float16* Ost = POOL + w * 3072;                 // 8 x 3072 halfs = whole ring
    _Float16* pp = Ppart + (size_t)slot * 4096;      // [32][128] row-major
#pragma unroll
    for (int t = 0; t < 2; ++t) {                    // pass t: regs t*8..t*8+7 -> rows t*16..
#pragma unroll
        for (int n = 0; n < 4; ++n)
#pragma unroll
            for (int rr = 0; rr < 8; ++rr) {
                int row = (rr & 3) + 8 * (rr >> 2) + 4 * lh;   // 0..15
                Ost[row * OSTLD + n * 32 + l31] = (_Float16)o[n][t * 8 + rr];
            }
#pragma unroll
        for (int i = 0; i < 4; ++i) {
            int idx = lane + i * 64;                 // half8-group: row=idx>>4, colgrp=idx&15
            half8 v = *(const half8*)&Ost[(idx >> 4) * OSTLD + (idx & 15) * 8];
            *(half8*)(pp + ((size_t)t * 2048 + (size_t)idx * 8)) = v;
        }
    }
}

// ---------------- kernel 2b: reduce partials + normalize ----------------
// grid 1024 (= B x 128 q-blocks), block 256. Sums <=8 fp16 partials, divides by l.
__global__ __launch_bounds__(256) void reduce_kernel(const _Float16* __restrict__ Ppart,
                                                     const float* __restrict__ Lpart,
                                                     float* __restrict__ out) {
    const int bid  = blockIdx.x;
    const int b    = bid >> 7;
    const int qt32 = bid & 127;
    const int qr0  = qt32 * 32;
    const int nch  = (((qr0 + 31) >> 6) >> 3) + 1;
    const int slot0 = b * SLOTS_PER_B + chunk_prefix(qt32);
    const _Float16* pp = Ppart + (size_t)slot0 * 4096;
    const float* lp = Lpart + (size_t)slot0 * 32;
    const int tid = threadIdx.x;

#pragma unroll
    for (int j = 0; j < 2; ++j) {
        int idx = tid + j * 256;            // half8 group 0..511
        int row = idx >> 4;
        float acc[8] = {0.f, 0.f, 0.f, 0.f, 0.f, 0.f, 0.f, 0.f};
        float l = 0.f;
        for (int c = 0; c < nch; ++c) {
            half8 v = *(const half8*)(pp + (size_t)c * 4096 + (size_t)idx * 8);
#pragma unroll
            for (int k = 0; k < 8; ++k) acc[k] += (float)v[k];
            l += lp[c * 32 + row];
        }
        float inv = 1.0f / l;
        float* ob = out + ((size_t)(b * S_) + qr0) * 128 + (size_t)idx * 8;
        floatx4 o0 = (floatx4){acc[0] * inv, acc[1] * inv, acc[2] * inv, acc[3] * inv};
        floatx4 o1 = (floatx4){acc[4] * inv, acc[5] * inv, acc[6] * inv, acc[7] * inv};
        *(floatx4*)ob = o0;
        *(floatx4*)(ob + 4) = o1;
    }
}

// ---------------- fallback path (ws too small): legacy layouts + atomics ----------------
#define PLD 72
__global__ __launch_bounds__(256) void prep_legacy_kernel(const float* __restrict__ qkv,
                                                          _Float16* __restrict__ Qh,
                                                          _Float16* __restrict__ Kp,
                                                          _Float16* __restrict__ Vp) {
    __shared__ __align__(16) _Float16 Kl[16][KW];
    __shared__ __align__(16) _Float16 Vt[128][VW];
    const int tid = threadIdx.x;
    const int b   = blockIdx.y;
    const int s0  = blockIdx.x * 16;
#pragma unroll
    for (int it = 0; it < 4; ++it) {
        int idx = tid + it * 256;
        int i = idx & 63, sr = idx >> 6, s = s0 + sr;
        const float* base = qkv + ((size_t)(b * S_ + s)) * 384 + 2 * i;
        floatx2 q2 = *(const floatx2*)base;
        floatx2 k2 = *(const floatx2*)(base + 128);
        float inv = exp2f(-(float)(2 * i) * L2_10K_OVER_128);
        float ang = (float)s * inv;
        float sn, cs;
        __sincosf(ang, &sn, &cs);
        size_t oq = ((size_t)(b * S_ + s)) * 128 + 2 * i;
        Qh[oq]     = (_Float16)((q2[0] * cs - q2[1] * sn) * SCALE_L2E);
        Qh[oq + 1] = (_Float16)((q2[0] * sn + q2[1] * cs) * SCALE_L2E);
        Kl[sr][2 * i]     = (_Float16)(k2[0] * cs - k2[1] * sn);
        Kl[sr][2 * i + 1] = (_Float16)(k2[0] * sn + k2[1] * cs);
    }
#pragma unroll
    for (int it = 0; it < 2; ++it) {
        int idx = tid + it * 256;
        int c = idx & 31, sr = idx >> 5;
        floatx4 v = *(const floatx4*)(qkv + ((size_t)(b * S_ + s0 + sr)) * 384 + 256 + c * 4);
#pragma unroll
        for (int j = 0; j < 4; ++j) Vt[c * 4 + j][sr] = (_Float16)v[j];
    }
    __syncthreads();
    {
        int c = tid >> 6, lane = tid & 63;
        int quad = lane >> 4, n = lane & 15;
        half8 val = *(const half8*)&Kl[n][c * 32 + quad * 8];
        int s16 = s0 >> 4;
        *(half8*)(Kp + (((size_t)(b * 256 + s16) * 4 + c) * 64 + lane) * 8) = val;
    }
    {
        int kt = s0 >> 6, c2 = (s0 >> 5) & 1, qp = (s0 >> 4) & 1;
        int nt = tid >> 5, lq = (tid >> 4) & 1, n = tid & 15;
        int quad = qp * 2 + lq;
        int lane = quad * 16 + n;
        half8 val = *(const half8*)&Vt[nt * 16 + n][lq * 8];
        *(half8*)(Vp + ((((size_t)(b * 64 + kt) * 2 + c2) * 8 + nt) * 64 + lane) * 8) = val;
    }
}

__global__ __launch_bounds__(64) void attn_atomic_kernel(const _Float16* __restrict__ Qh,
                                                         const _Float16* __restrict__ Kp,
                                                         const _Float16* __restrict__ Vp,
                                                         float* __restrict__ out,
                                                         float* __restrict__ Lg) {
    __shared__ __align__(16) _Float16 Pl[2][16 * PLD];
    const int lane = threadIdx.x, quad = lane >> 4, l16 = lane & 15;
    const int b = blockIdx.x & 7, chunk = blockIdx.x >> 3;
    const int qt = 255 - blockIdx.y, qr0 = qt * 16;
    const int kt_max = qt >> 2, c0 = chunk * 8;
    if (c0 > kt_max) return;
    const int kend = min(kt_max, c0 + 7);
    const _Float16* Qb = Qh + ((size_t)(b * S_) + qr0 + l16) * 128;
    half8 aq[4];
#pragma unroll
    for (int c = 0; c < 4; ++c) aq[c] = *(const half8*)(Qb + c * 32 + quad * 8);
    floatx4 o[8];
#pragma unroll
    for (int i = 0; i < 8; ++i) o[i] = (floatx4){0.f, 0.f, 0.f, 0.f};
    float rsum[4] = {0.f, 0.f, 0.f, 0.f};
    const _Float16* Kb = Kp + (size_t)b * 524288;
    const _Float16* Vb = Vp + (size_t)b * 524288;
    for (int kt = c0; kt <= kend; ++kt) {
        half8 vf[2][8];
#pragma unroll
        for (int c2 = 0; c2 < 2; ++c2)
#pragma unroll
            for (int nt = 0; nt < 8; ++nt)
                vf[c2][nt] = *(const half8*)(Vb + (((size_t)(kt * 2 + c2) * 8 + nt) * 64 + lane) * 8);
        floatx4 s4[4];
#pragma unroll
        for (int t = 0; t < 4; ++t) {
            const _Float16* kp = Kb + ((size_t)((kt * 4 + t) * 4) * 64 + lane) * 8;
            floatx4 acc = (floatx4){0.f, 0.f, 0.f, 0.f};
#pragma unroll
            for (int c = 0; c < 4; ++c) {
                half8 bk = *(const half8*)(kp + c * 512);
                acc = __builtin_amdgcn_mfma_f32_16x16x32_f16(aq[c], bk, acc, 0, 0, 0);
            }
            s4[t] = acc;
        }
        if (kt == kt_max) {
#pragma unroll
            for (int t = 0; t < 4; ++t)
#pragma unroll
                for (int r = 0; r < 4; ++r) {
                    int kcol = kt * 64 + t * 16 + l16;
                    int qr = qr0 + quad * 4 + r;
                    if (kcol > qr) s4[t][r] += MASK_L2E;
                }
        }
        const int buf = kt & 1;
#pragma unroll
        for (int t = 0; t < 4; ++t)
#pragma unroll
            for (int r = 0; r < 4; ++r) {
                float p = __builtin_amdgcn_exp2f(s4[t][r]);
                rsum[r] += p;
                Pl[buf][(quad * 4 + r) * PLD + t * 16 + l16] = (_Float16)p;
            }
#pragma unroll
        for (int c2 = 0; c2 < 2; ++c2) {
            half8 ap = *(const half8*)&Pl[buf][l16 * PLD + c2 * 32 + quad * 8];
#pragma unroll
            for (int nt = 0; nt < 8; ++nt)
                o[nt] = __builtin_amdgcn_mfma_f32_16x16x32_f16(ap, vf[c2][nt], o[nt], 0, 0, 0);
        }
    }
#pragma unroll
    for (int off = 1; off <= 8; off <<= 1)
#pragma unroll
        for (int r = 0; r < 4; ++r)
            rsum[r] += __shfl_xor(rsum[r], off, 64);
    if (l16 == 0) {
#pragma unroll
        for (int r = 0; r < 4; ++r)
            atomicAdd(&Lg[(size_t)(b * S_) + qr0 + quad * 4 + r], rsum[r]);
    }
    float* ob = out + ((size_t)(b * S_) + qr0) * 128;
#pragma unroll
    for (int nt = 0; nt < 8; ++nt)
#pragma unroll
        for (int r = 0; r < 4; ++r)
            atomicAdd(&ob[(quad * 4 + r) * 128 + nt * 16 + l16], o[nt][r]);
}

__global__ __launch_bounds__(256) void norm_kernel(float* __restrict__ out,
                                                   const float* __restrict__ Lg) {
    int i = blockIdx.x * 256 + threadIdx.x;
    int row = i >> 5;
    floatx4 v = *(floatx4*)(out + (size_t)i * 4);
    float inv = 1.0f / Lg[row];
    v[0] *= inv; v[1] *= inv; v[2] *= inv; v[3] *= inv;
    *(floatx4*)(out + (size_t)i * 4) = v;
}

extern "C" void kernel_launch(void* const* d_in, const int* in_sizes, int n_in,
                              void* d_out, int out_size, void* d_ws, size_t ws_size,
                              hipStream_t stream) {
    const float* qkv = (const float*)d_in[0];
    float* out = (float*)d_out;
    const size_t MB = 1024 * 1024;
    _Float16* Qh = (_Float16*)d_ws;                          // 8 MB
    _Float16* Kp = (_Float16*)((char*)d_ws + 8 * MB);        // 8 MB
    _Float16* Vp = (_Float16*)((char*)d_ws + 16 * MB);       // 8 MB

    const size_t ppart_bytes = (size_t)B_ * SLOTS_PER_B * 4096 * sizeof(_Float16); // 36 MB
    const size_t need = 25 * MB + ppart_bytes;

    if (ws_size >= need) {
        float*    Lpart = (float*)((char*)d_ws + 24 * MB);       // 576 KB
        _Float16* Ppart = (_Float16*)((char*)d_ws + 25 * MB);    // 36 MB
        prep_kernel<<<dim3(256, B_), dim3(256), 0, stream>>>(qkv, Qh, Kp, Vp);
        attn_part_kernel<<<dim3(64, 16), dim3(512), 0, stream>>>(Qh, Kp, Vp, Ppart, Lpart);
        reduce_kernel<<<dim3(1024), dim3(256), 0, stream>>>(Ppart, Lpart, out);
    } else {
        prep_legacy_kernel<<<dim3(256, B_), dim3(256), 0, stream>>>(qkv, Qh, Kp, Vp);
        float* Lg = (float*)((char*)d_ws + 24 * MB);             // 128 KB
        hipMemsetAsync(out, 0, (size_t)B_ * S_ * 128 * sizeof(float), stream);
        hipMemsetAsync(Lg, 0, (size_t)B_ * S_ * sizeof(float), stream);
        attn_atomic_kernel<<<dim3(64, 256), dim3(64), 0, stream>>>(Qh, Kp, Vp, out, Lg);
        norm_kernel<<<dim3(4096), dim3(256), 0, stream>>>(out, Lg);
    }
}

// Round 12
// 151.612 us; speedup vs baseline: 2.1498x; 1.0062x over previous
//
#include <hip/hip_runtime.h>
#include <math.h>

typedef _Float16 half8 __attribute__((ext_vector_type(8)));
typedef float floatx4 __attribute__((ext_vector_type(4)));
typedef float floatx16 __attribute__((ext_vector_type(16)));
typedef float floatx2 __attribute__((ext_vector_type(2)));

#define B_ 8
#define S_ 4096
// scale = 1/sqrt(128) * log2(e): folded into Q so softmax exp is one v_exp_f32
#define SCALE_L2E 0.12751743008389106f
#define MASK_L2E  -14426.950408889634f   // -10000*log2(e): exp2 -> exact 0
#define L2_10K_OVER_128 0.10381025296522975f  // log2(10000)/128

#define KW  136   // prep K LDS row stride (halfs)
#define VW  24    // prep V^T LDS row stride (halfs)
#define OSTLD 136 // O-staging LDS row stride (halfs)
#define SLOTS_PER_B 576   // sum over qt32 of ceil(tiles/8)
#define NW 8      // waves per attn block
#define KVBUF 8192   // halfs per ring buffer: K 4096 | V 4096 (16KB)
#define NBUF 3       // 3-deep ring: single barrier per phase + depth-2 prefetch
#define POOL_HALFS (NBUF * KVBUF)   // 24576 halfs = 49152 B (P never touches LDS)

// units before q-block qt32 (chunks = floor(qt32/16)+1)
__device__ __forceinline__ int chunk_prefix(int qt32) {
    int g = qt32 >> 4;
    return qt32 + 8 * g * (g - 1) + (qt32 - (g << 4)) * g;
}

// async global->LDS, 16B per lane, wave-uniform LDS base (HW adds lane*16)
__device__ __forceinline__ void glds16(const _Float16* src, _Float16* dst) {
    __builtin_amdgcn_global_load_lds((const __attribute__((address_space(1))) void*)src,
                                     (__attribute__((address_space(3))) void*)dst, 16, 0, 0);
}

// pack two f32 -> one u32 of two fp16 (low half = first arg)
__device__ __forceinline__ unsigned pack2(float a, float b) {
    union { _Float16 h[2]; unsigned u; } x;
    x.h[0] = (_Float16)a; x.h[1] = (_Float16)b;
    return x.u;
}

// ---------------- kernel 1: prep (32x32-fragment layouts) ----------------
// grid (256, 8), block 256: 16 seq rows per block.
//  Qh: RoPE(Q)*SCALE_L2E fp16 row-major [b][s][d]  (unchanged)
//  Kp32: per 32-row half-tile ht, d-step c(0..7):
//        chunk(b,ht,c)[lane][j] = K[ht*32 + (lane&31)][c*16 + (lane>>5)*8 + j]
//        -> direct A-frag for mfma_32x32x16 (M=k-rows)
//  Vp32: per ht, k-step s(0..1), d-tile n(0..3):
//        chunk(b,ht,s*4+n)[lane][j] = V[ht*32 + s*16 + (lane>>5)*8 + j][n*32 + (lane&31)]
//        -> direct B-frag for PV mfma_32x32x16 (N=d)
__global__ __launch_bounds__(256) void prep_kernel(const float* __restrict__ qkv,
                                                   _Float16* __restrict__ Qh,
                                                   _Float16* __restrict__ Kp,
                                                   _Float16* __restrict__ Vp) {
    __shared__ __align__(16) _Float16 Kl[16][KW];
    __shared__ __align__(16) _Float16 Vt[128][VW];
    const int tid = threadIdx.x;
    const int b   = blockIdx.y;
    const int s0  = blockIdx.x * 16;

#pragma unroll
    for (int it = 0; it < 4; ++it) {
        int idx = tid + it * 256;
        int i = idx & 63, sr = idx >> 6, s = s0 + sr;
        const float* base = qkv + ((size_t)(b * S_ + s)) * 384 + 2 * i;
        floatx2 q2 = *(const floatx2*)base;
        floatx2 k2 = *(const floatx2*)(base + 128);
        float inv = exp2f(-(float)(2 * i) * L2_10K_OVER_128);
        float ang = (float)s * inv;
        float sn, cs;
        __sincosf(ang, &sn, &cs);
        size_t oq = ((size_t)(b * S_ + s)) * 128 + 2 * i;
        Qh[oq]     = (_Float16)((q2[0] * cs - q2[1] * sn) * SCALE_L2E);
        Qh[oq + 1] = (_Float16)((q2[0] * sn + q2[1] * cs) * SCALE_L2E);
        Kl[sr][2 * i]     = (_Float16)(k2[0] * cs - k2[1] * sn);
        Kl[sr][2 * i + 1] = (_Float16)(k2[0] * sn + k2[1] * cs);
    }
#pragma unroll
    for (int it = 0; it < 2; ++it) {
        int idx = tid + it * 256;
        int c = idx & 31, sr = idx >> 5;
        floatx4 v = *(const floatx4*)(qkv + ((size_t)(b * S_ + s0 + sr)) * 384 + 256 + c * 4);
#pragma unroll
        for (int j = 0; j < 4; ++j) Vt[c * 4 + j][sr] = (_Float16)v[j];
    }
    __syncthreads();

    const int ht = s0 >> 5;
    {   // K 32x32 A-frag-major out: tid -> g = d-group(0..15), sr = row(0..15)
        int g = tid >> 4, sr = tid & 15;
        int r = s0 + sr;
        int c = g >> 1, dh = g & 1;
        int l = (r & 31) + (dh << 5);
        half8 val = *(const half8*)&Kl[sr][g * 8];
        *(half8*)(Kp + (((size_t)(b * 128 + ht) * 8 + c) * 64 + l) * 8) = val;
    }
    {   // V 32x32 B-frag-major out: tid -> n = d-tile(0..3), l = lane(0..63)
        int n = tid >> 6, l = tid & 63;
        int sh = (s0 >> 4) & 1;             // which k-step half of ht this block covers
        half8 val = *(const half8*)&Vt[n * 32 + (l & 31)][(l >> 5) * 8];
        *(half8*)(Vp + (((size_t)(b * 128 + ht) * 8 + sh * 4 + n) * 64 + l) * 8) = val;
    }
}

// ---------------- kernel 2a: split-K flash, 32x32 MFMA + in-register P ----------------
// R11 verified (61.2us, bank-conflicts 680k->147k): skeleton = R5 ring; swapped
// QK^T with mfma_f32_32x32x16_f16 -> exp2 -> pack -> 4x v_permlane32_swap (pure
// VALU cross-lane) builds the PV A-frag in registers. P never touches LDS.
// UNCHANGED THIS ROUND (rule: one subsystem per round; co-compile perturbation).
__global__ __launch_bounds__(512) void attn_part_kernel(const _Float16* __restrict__ Qh,
                                                        const _Float16* __restrict__ Kp,
                                                        const _Float16* __restrict__ Vp,
                                                        _Float16* __restrict__ Ppart,
                                                        float* __restrict__ Lpart) {
    __shared__ __align__(16) _Float16 POOL[POOL_HALFS];

    const int tid  = threadIdx.x;
    const int w    = tid >> 6;
    const int lane = tid & 63;
    const int l31  = lane & 31;
    const int lh   = lane >> 5;
    const int b     = blockIdx.x & 7;
    const int chunk = blockIdx.x >> 3;
    const int c0    = chunk * 8;

    const int qt32_top  = 127 - blockIdx.y * 8;          // wave 0's qt32 (largest in block)
    const int ktmax_blk = (qt32_top * 32 + 31) >> 6;
    if (c0 > ktmax_blk) return;                          // uniform: whole block exits
    const int kend_blk  = min(ktmax_blk, c0 + 7);

    const int qt32   = qt32_top - w;
    const int qr0    = qt32 * 32;
    const int kt_max = (qr0 + 31) >> 6;
    const bool has_work = (c0 <= kt_max);
    const int kend   = min(kt_max, c0 + 7);
    const int slot   = b * SLOTS_PER_B + chunk_prefix(qt32) + chunk;

    // Q B-frags (col q = l31, d = c*16 + lh*8 + j): contiguous half8 from row-major Qh
    half8 aq[8];
    {
        const _Float16* Qb = Qh + ((size_t)(b * S_) + qr0 + l31) * 128 + lh * 8;
#pragma unroll
        for (int c = 0; c < 8; ++c) aq[c] = *(const half8*)(Qb + c * 16);
    }

    floatx16 o[4];
#pragma unroll
    for (int n = 0; n < 4; ++n)
#pragma unroll
        for (int r = 0; r < 16; ++r) o[n][r] = 0.f;
    float rsum = 0.f;   // per-lane partial row-sum for q = l31 (this lane-half's k's)

    const _Float16* Kb = Kp + (size_t)b * 524288;
    const _Float16* Vb = Vp + (size_t)b * 524288;

    const int ht0    = 2 * c0;            // half-tile index = kt*2 + h; K/V halfs at ht*4096
    const int ht_end = 2 * kend_blk + 1;  // >= ht0+1 always

    // stage half-tile ht_ into ring buffer ht_%3 (wave w moves 1KB K + 1KB V)
#define STAGE(ht_)                                                                \
    do {                                                                          \
        const _Float16* ks_ = Kb + (size_t)(ht_) * 4096 + w * 512 + lane * 8;     \
        const _Float16* vs_ = Vb + (size_t)(ht_) * 4096 + w * 512 + lane * 8;     \
        _Float16* d_ = POOL + ((ht_) % NBUF) * KVBUF + w * 512;                   \
        glds16(ks_, d_);                                                          \
        glds16(vs_, d_ + 4096);                                                   \
    } while (0)

    // prologue: stage the first two half-tiles (4 loads in flight)
    STAGE(ht0);
    STAGE(ht0 + 1);

    for (int ht = ht0; ht <= ht_end; ++ht) {
        if (ht < ht_end) {
            asm volatile("s_waitcnt vmcnt(2)" ::: "memory");  // buf[ht%3] loads retired
        } else {
            asm volatile("s_waitcnt vmcnt(0)" ::: "memory");
        }
        __builtin_amdgcn_s_barrier();
        if (ht + 2 <= ht_end) STAGE(ht + 2);

        const int kt = ht >> 1;
        if (has_work && kt <= kend) {
            const _Float16* Klds = POOL + (ht % NBUF) * KVBUF;
            const _Float16* Vlds = Klds + 4096;

            // S^T = K Q^T over d=0..127 (8 accumulating 32x32x16 MFMAs)
            floatx16 Cs;
#pragma unroll
            for (int r = 0; r < 16; ++r) Cs[r] = 0.f;
#pragma unroll
            for (int c = 0; c < 8; ++c) {
                half8 ak = *(const half8*)&Klds[(c * 64 + lane) * 8];
                Cs = __builtin_amdgcn_mfma_f32_32x32x16_f16(ak, aq[c], Cs, 0, 0, 0);
            }

            // V B-frags: issue EARLY so ds_read latency hides under the VALU section
            half8 bv[8];
#pragma unroll
            for (int i = 0; i < 8; ++i)
                bv[i] = *(const half8*)&Vlds[(i * 64 + lane) * 8];

            if (kt == kt_max) {  // causal mask (diagonal half-tiles only)
#pragma unroll
                for (int r = 0; r < 16; ++r) {
                    int kl = (r & 3) + 8 * (r >> 2) + 4 * lh;
                    if (ht * 32 + kl > qr0 + l31) Cs[r] += MASK_L2E;
                }
            }

            // exp2 -> pack f16 pairs -> permlane32_swap builds PV A-frags in regs
            float e[16];
#pragma unroll
            for (int r = 0; r < 16; ++r) {
                e[r] = __builtin_amdgcn_exp2f(Cs[r]);
                rsum += e[r];
            }
            unsigned A0 = pack2(e[0], e[1]),  B0 = pack2(e[2], e[3]);
            unsigned C0 = pack2(e[4], e[5]),  D0 = pack2(e[6], e[7]);
            unsigned A1 = pack2(e[8], e[9]),  B1 = pack2(e[10], e[11]);
            unsigned C1 = pack2(e[12], e[13]), D1 = pack2(e[14], e[15]);
            // D.hi <-> S.lo : after swap(X,Y): X = [X_lo | Y_lo_from_lo_lanes],
            // Y = [X_hi_from_hi_lanes | Y_hi]. Verified word map for A-frag
            // (q=l31, k=step*16+lh*8+j) in all four lane-half x step quadrants.
            asm("v_permlane32_swap_b32 %0, %1" : "+v"(A0), "+v"(C0));
            asm("v_permlane32_swap_b32 %0, %1" : "+v"(B0), "+v"(D0));
            asm("v_permlane32_swap_b32 %0, %1" : "+v"(A1), "+v"(C1));
            asm("v_permlane32_swap_b32 %0, %1" : "+v"(B1), "+v"(D1));
            union { unsigned u[4]; half8 v; } pa0, pa1;
            pa0.u[0] = A0; pa0.u[1] = B0; pa0.u[2] = C0; pa0.u[3] = D0;
            pa1.u[0] = A1; pa1.u[1] = B1; pa1.u[2] = C1; pa1.u[3] = D1;

            // O += P V  (2 k-steps x 4 d-tiles)
#pragma unroll
            for (int n = 0; n < 4; ++n)
                o[n] = __builtin_amdgcn_mfma_f32_32x32x16_f16(pa0.v, bv[n], o[n], 0, 0, 0);
#pragma unroll
            for (int n = 0; n < 4; ++n)
                o[n] = __builtin_amdgcn_mfma_f32_32x32x16_f16(pa1.v, bv[4 + n], o[n], 0, 0, 0);
        }
    }
#undef STAGE

    // protect POOL reuse below: all waves done reading the ring
    __builtin_amdgcn_s_barrier();

    if (!has_work) return;

    // row sums: lane-half pair (l, l+32) covers all 32 k per phase -> one xor-32 add
    rsum += __shfl_xor(rsum, 32, 64);
    if (lane < 32) Lpart[(size_t)slot * 32 + lane] = rsum;

    // O partial: C rows q = (r&3)+8*(r>>2)+4*lh, cols n*32+l31 -> LDS fp16
    // staging (16 rows/pass, per-wave slice) -> coalesced 16B streaming stores.
    _Float16* Ost = POOL + w * 3072;                 // 8 x 3072 halfs = whole ring
    _Float16* pp = Ppart + (size_t)slot * 4096;      // [32][128] row-major
#pragma unroll
    for (int t = 0; t < 2; ++t) {                    // pass t: regs t*8..t*8+7 -> rows t*16..
#pragma unroll
        for (int n = 0; n < 4; ++n)
#pragma unroll
            for (int rr = 0; rr < 8; ++rr) {
                int row = (rr & 3) + 8 * (rr >> 2) + 4 * lh;   // 0..15
                Ost[row * OSTLD + n * 32 + l31] = (_Float16)o[n][t * 8 + rr];
            }
#pragma unroll
        for (int i = 0; i < 4; ++i) {
            int idx = lane + i * 64;                 // half8-group: row=idx>>4, colgrp=idx&15
            half8 v = *(const half8*)&Ost[(idx >> 4) * OSTLD + (idx & 15) * 8];
            *(half8*)(pp + ((size_t)t * 2048 + (size_t)idx * 8)) = v;
        }
    }
}

// ---------------- kernel 2b: reduce partials + normalize ----------------
// R12: grid (1024, 2), block 256; x -> b = x&7 (XCD affinity: reduce block's XCD
// == XCD that wrote this b's Ppart -> L2-warm reads), qt32 = x>>3; y = j half.
// Chunk loop UNROLLED to fixed 8 with clamped addresses + predicate weight:
// all 8 loads issue independently (old runtime-bound loop serialized ~nch
// exposed load latencies per thread -- reduce ran at 2.4x its traffic floor).
__global__ __launch_bounds__(256) void reduce_kernel(const _Float16* __restrict__ Ppart,
                                                     const float* __restrict__ Lpart,
                                                     float* __restrict__ out) {
    const int x    = blockIdx.x;
    const int b    = x & 7;
    const int qt32 = x >> 3;
    const int qr0  = qt32 * 32;
    const int nch  = (((qr0 + 31) >> 6) >> 3) + 1;
    const int slot0 = b * SLOTS_PER_B + chunk_prefix(qt32);
    const _Float16* pp = Ppart + (size_t)slot0 * 4096;
    const float* lp = Lpart + (size_t)slot0 * 32;

    const int idx = threadIdx.x + blockIdx.y * 256;   // half8 group 0..511
    const int row = idx >> 4;
    float acc[8] = {0.f, 0.f, 0.f, 0.f, 0.f, 0.f, 0.f, 0.f};
    float l = 0.f;
#pragma unroll
    for (int c = 0; c < 8; ++c) {
        int cc = (c < nch) ? c : (nch - 1);           // clamped: address always valid
        float wgt = (c < nch) ? 1.f : 0.f;            // predicate, not branch
        half8 v = *(const half8*)(pp + (size_t)cc * 4096 + (size_t)idx * 8);
        float lv = lp[cc * 32 + row];
#pragma unroll
        for (int k = 0; k < 8; ++k) acc[k] += wgt * (float)v[k];
        l += wgt * lv;
    }
    float inv = 1.0f / l;
    float* ob = out + ((size_t)(b * S_) + qr0) * 128 + (size_t)idx * 8;
    floatx4 o0 = (floatx4){acc[0] * inv, acc[1] * inv, acc[2] * inv, acc[3] * inv};
    floatx4 o1 = (floatx4){acc[4] * inv, acc[5] * inv, acc[6] * inv, acc[7] * inv};
    *(floatx4*)ob = o0;
    *(floatx4*)(ob + 4) = o1;
}

// ---------------- fallback path (ws too small): legacy layouts + atomics ----------------
#define PLD 72
__global__ __launch_bounds__(256) void prep_legacy_kernel(const float* __restrict__ qkv,
                                                          _Float16* __restrict__ Qh,
                                                          _Float16* __restrict__ Kp,
                                                          _Float16* __restrict__ Vp) {
    __shared__ __align__(16) _Float16 Kl[16][KW];
    __shared__ __align__(16) _Float16 Vt[128][VW];
    const int tid = threadIdx.x;
    const int b   = blockIdx.y;
    const int s0  = blockIdx.x * 16;
#pragma unroll
    for (int it = 0; it < 4; ++it) {
        int idx = tid + it * 256;
        int i = idx & 63, sr = idx >> 6, s = s0 + sr;
        const float* base = qkv + ((size_t)(b * S_ + s)) * 384 + 2 * i;
        floatx2 q2 = *(const floatx2*)base;
        floatx2 k2 = *(const floatx2*)(base + 128);
        float inv = exp2f(-(float)(2 * i) * L2_10K_OVER_128);
        float ang = (float)s * inv;
        float sn, cs;
        __sincosf(ang, &sn, &cs);
        size_t oq = ((size_t)(b * S_ + s)) * 128 + 2 * i;
        Qh[oq]     = (_Float16)((q2[0] * cs - q2[1] * sn) * SCALE_L2E);
        Qh[oq + 1] = (_Float16)((q2[0] * sn + q2[1] * cs) * SCALE_L2E);
        Kl[sr][2 * i]     = (_Float16)(k2[0] * cs - k2[1] * sn);
        Kl[sr][2 * i + 1] = (_Float16)(k2[0] * sn + k2[1] * cs);
    }
#pragma unroll
    for (int it = 0; it < 2; ++it) {
        int idx = tid + it * 256;
        int c = idx & 31, sr = idx >> 5;
        floatx4 v = *(const floatx4*)(qkv + ((size_t)(b * S_ + s0 + sr)) * 384 + 256 + c * 4);
#pragma unroll
        for (int j = 0; j < 4; ++j) Vt[c * 4 + j][sr] = (_Float16)v[j];
    }
    __syncthreads();
    {
        int c = tid >> 6, lane = tid & 63;
        int quad = lane >> 4, n = lane & 15;
        half8 val = *(const half8*)&Kl[n][c * 32 + quad * 8];
        int s16 = s0 >> 4;
        *(half8*)(Kp + (((size_t)(b * 256 + s16) * 4 + c) * 64 + lane) * 8) = val;
    }
    {
        int kt = s0 >> 6, c2 = (s0 >> 5) & 1, qp = (s0 >> 4) & 1;
        int nt = tid >> 5, lq = (tid >> 4) & 1, n = tid & 15;
        int quad = qp * 2 + lq;
        int lane = quad * 16 + n;
        half8 val = *(const half8*)&Vt[nt * 16 + n][lq * 8];
        *(half8*)(Vp + ((((size_t)(b * 64 + kt) * 2 + c2) * 8 + nt) * 64 + lane) * 8) = val;
    }
}

__global__ __launch_bounds__(64) void attn_atomic_kernel(const _Float16* __restrict__ Qh,
                                                         const _Float16* __restrict__ Kp,
                                                         const _Float16* __restrict__ Vp,
                                                         float* __restrict__ out,
                                                         float* __restrict__ Lg) {
    __shared__ __align__(16) _Float16 Pl[2][16 * PLD];
    const int lane = threadIdx.x, quad = lane >> 4, l16 = lane & 15;
    const int b = blockIdx.x & 7, chunk = blockIdx.x >> 3;
    const int qt = 255 - blockIdx.y, qr0 = qt * 16;
    const int kt_max = qt >> 2, c0 = chunk * 8;
    if (c0 > kt_max) return;
    const int kend = min(kt_max, c0 + 7);
    const _Float16* Qb = Qh + ((size_t)(b * S_) + qr0 + l16) * 128;
    half8 aq[4];
#pragma unroll
    for (int c = 0; c < 4; ++c) aq[c] = *(const half8*)(Qb + c * 32 + quad * 8);
    floatx4 o[8];
#pragma unroll
    for (int i = 0; i < 8; ++i) o[i] = (floatx4){0.f, 0.f, 0.f, 0.f};
    float rsum[4] = {0.f, 0.f, 0.f, 0.f};
    const _Float16* Kb = Kp + (size_t)b * 524288;
    const _Float16* Vb = Vp + (size_t)b * 524288;
    for (int kt = c0; kt <= kend; ++kt) {
        half8 vf[2][8];
#pragma unroll
        for (int c2 = 0; c2 < 2; ++c2)
#pragma unroll
            for (int nt = 0; nt < 8; ++nt)
                vf[c2][nt] = *(const half8*)(Vb + (((size_t)(kt * 2 + c2) * 8 + nt) * 64 + lane) * 8);
        floatx4 s4[4];
#pragma unroll
        for (int t = 0; t < 4; ++t) {
            const _Float16* kp = Kb + ((size_t)((kt * 4 + t) * 4) * 64 + lane) * 8;
            floatx4 acc = (floatx4){0.f, 0.f, 0.f, 0.f};
#pragma unroll
            for (int c = 0; c < 4; ++c) {
                half8 bk = *(const half8*)(kp + c * 512);
                acc = __builtin_amdgcn_mfma_f32_16x16x32_f16(aq[c], bk, acc, 0, 0, 0);
            }
            s4[t] = acc;
        }
        if (kt == kt_max) {
#pragma unroll
            for (int t = 0; t < 4; ++t)
#pragma unroll
                for (int r = 0; r < 4; ++r) {
                    int kcol = kt * 64 + t * 16 + l16;
                    int qr = qr0 + quad * 4 + r;
                    if (kcol > qr) s4[t][r] += MASK_L2E;
                }
        }
        const int buf = kt & 1;
#pragma unroll
        for (int t = 0; t < 4; ++t)
#pragma unroll
            for (int r = 0; r < 4; ++r) {
                float p = __builtin_amdgcn_exp2f(s4[t][r]);
                rsum[r] += p;
                Pl[buf][(quad * 4 + r) * PLD + t * 16 + l16] = (_Float16)p;
            }
#pragma unroll
        for (int c2 = 0; c2 < 2; ++c2) {
            half8 ap = *(const half8*)&Pl[buf][l16 * PLD + c2 * 32 + quad * 8];
#pragma unroll
            for (int nt = 0; nt < 8; ++nt)
                o[nt] = __builtin_amdgcn_mfma_f32_16x16x32_f16(ap, vf[c2][nt], o[nt], 0, 0, 0);
        }
    }
#pragma unroll
    for (int off = 1; off <= 8; off <<= 1)
#pragma unroll
        for (int r = 0; r < 4; ++r)
            rsum[r] += __shfl_xor(rsum[r], off, 64);
    if (l16 == 0) {
#pragma unroll
        for (int r = 0; r < 4; ++r)
            atomicAdd(&Lg[(size_t)(b * S_) + qr0 + quad * 4 + r], rsum[r]);
    }
    float* ob = out + ((size_t)(b * S_) + qr0) * 128;
#pragma unroll
    for (int nt = 0; nt < 8; ++nt)
#pragma unroll
        for (int r = 0; r < 4; ++r)
            atomicAdd(&ob[(quad * 4 + r) * 128 + nt * 16 + l16], o[nt][r]);
}

__global__ __launch_bounds__(256) void norm_kernel(float* __restrict__ out,
                                                   const float* __restrict__ Lg) {
    int i = blockIdx.x * 256 + threadIdx.x;
    int row = i >> 5;
    floatx4 v = *(floatx4*)(out + (size_t)i * 4);
    float inv = 1.0f / Lg[row];
    v[0] *= inv; v[1] *= inv; v[2] *= inv; v[3] *= inv;
    *(floatx4*)(out + (size_t)i * 4) = v;
}

extern "C" void kernel_launch(void* const* d_in, const int* in_sizes, int n_in,
                              void* d_out, int out_size, void* d_ws, size_t ws_size,
                              hipStream_t stream) {
    const float* qkv = (const float*)d_in[0];
    float* out = (float*)d_out;
    const size_t MB = 1024 * 1024;
    _Float16* Qh = (_Float16*)d_ws;                          // 8 MB
    _Float16* Kp = (_Float16*)((char*)d_ws + 8 * MB);        // 8 MB
    _Float16* Vp = (_Float16*)((char*)d_ws + 16 * MB);       // 8 MB

    const size_t ppart_bytes = (size_t)B_ * SLOTS_PER_B * 4096 * sizeof(_Float16); // 36 MB
    const size_t need = 25 * MB + ppart_bytes;

    if (ws_size >= need) {
        float*    Lpart = (float*)((char*)d_ws + 24 * MB);       // 576 KB
        _Float16* Ppart = (_Float16*)((char*)d_ws + 25 * MB);    // 36 MB
        prep_kernel<<<dim3(256, B_), dim3(256), 0, stream>>>(qkv, Qh, Kp, Vp);
        attn_part_kernel<<<dim3(64, 16), dim3(512), 0, stream>>>(Qh, Kp, Vp, Ppart, Lpart);
        reduce_kernel<<<dim3(1024, 2), dim3(256), 0, stream>>>(Ppart, Lpart, out);
    } else {
        prep_legacy_kernel<<<dim3(256, B_), dim3(256), 0, stream>>>(qkv, Qh, Kp, Vp);
        float* Lg = (float*)((char*)d_ws + 24 * MB);             // 128 KB
        hipMemsetAsync(out, 0, (size_t)B_ * S_ * 128 * sizeof(float), stream);
        hipMemsetAsync(Lg, 0, (size_t)B_ * S_ * sizeof(float), stream);
        attn_atomic_kernel<<<dim3(64, 256), dim3(64), 0, stream>>>(Qh, Kp, Vp, out, Lg);
        norm_kernel<<<dim3(4096), dim3(256), 0, stream>>>(out, Lg);
    }
}